// Round 1
// baseline (7386.185 us; speedup 1.0000x reference)
//
#include <hip/hip_runtime.h>
#include <cstdint>
#include <cstddef>

#define N_NODES 100000
#define N_EDGES 1600000
#define H 128
#define L_LAYERS 5
#define G_GRAPHS 128
#define OUT_F 128
#define BN_EPS 1e-5f

__device__ __forceinline__ float frelu(float x) { return fmaxf(x, 0.0f); }

// ---------------- degree ----------------
__global__ void init_deg(float* deg) {
    int i = blockIdx.x * 256 + threadIdx.x;
    if (i < N_NODES) deg[i] = 1.0f;
}

__global__ void count_deg(const int* __restrict__ row, float* __restrict__ deg) {
    int e = blockIdx.x * 256 + threadIdx.x;   // E divisible by 256
    unsafeAtomicAdd(&deg[row[e]], 1.0f);
}

__global__ void finish_deg(const float* __restrict__ deg, float* __restrict__ dis,
                           float* __restrict__ invdeg) {
    int i = blockIdx.x * 256 + threadIdx.x;
    if (i < N_NODES) {
        float d = deg[i];
        dis[i] = 1.0f / sqrtf(d);
        invdeg[i] = 1.0f / d;
    }
}

// ---------------- h init: h[i] = node_emb[x[i]] ----------------
__global__ void init_h(const int* __restrict__ x, const float* __restrict__ nemb,
                       float* __restrict__ h) {
    size_t idx = (size_t)blockIdx.x * 256 + threadIdx.x;  // float4 index, N*H/4 total
    int node = (int)(idx >> 5);
    int c0 = ((int)idx & 31) * 4;
    int xv = x[node];
    float4 v = *(const float4*)(nemb + (size_t)xv * H + c0);
    ((float4*)h)[idx] = v;
}

// ---------------- xl = h @ W + b  (fp32, LDS-tiled) ----------------
// block = 256 threads, tile = 128 rows x 128 cols, per-thread 8x8, K chunks of 32
__global__ __launch_bounds__(256) void gemm_xl(const float* __restrict__ hin,
                                               const float* __restrict__ Wl,
                                               const float* __restrict__ bl,
                                               float* __restrict__ xlo) {
    constexpr int KC = 32;
    constexpr int HPITCH = 33;   // [row][k]  banks: row stride 33*? -> ty*8*33 % 32 = 8*ty
    constexpr int WPITCH = 132;  // [k][c], float4-aligned pitch
    __shared__ float sH[128 * HPITCH];   // 16.9 KB
    __shared__ float sW[KC * WPITCH];    // 16.9 KB
    int t = threadIdx.x;
    int tx = t & 15, ty = t >> 4;
    int r0 = blockIdx.x * 128;
    int c0 = tx * 8;
    int rbase = ty * 8;
    float acc[8][8];
#pragma unroll
    for (int i = 0; i < 8; i++)
#pragma unroll
        for (int j = 0; j < 8; j++) acc[i][j] = 0.0f;

    for (int kc = 0; kc < H; kc += KC) {
        // stage h tile: 128 rows x 32 k = 1024 float4
        for (int idx = t; idx < 1024; idx += 256) {
            int rowi = idx >> 3;       // /8 float4-groups
            int kg = idx & 7;
            int gr = r0 + rowi; if (gr > N_NODES - 1) gr = N_NODES - 1;
            float4 v = *(const float4*)(hin + (size_t)gr * H + kc + kg * 4);
            float* d = &sH[rowi * HPITCH + kg * 4];
            d[0] = v.x; d[1] = v.y; d[2] = v.z; d[3] = v.w;
        }
        // stage W tile: 32 k x 128 c = 1024 float4
        for (int idx = t; idx < 1024; idx += 256) {
            int k = idx >> 5;
            int cg = idx & 31;
            *(float4*)&sW[k * WPITCH + cg * 4] =
                *(const float4*)(Wl + (size_t)(kc + k) * H + cg * 4);
        }
        __syncthreads();
#pragma unroll 4
        for (int k = 0; k < KC; k++) {
            float4 w0 = *(const float4*)&sW[k * WPITCH + c0];
            float4 w1 = *(const float4*)&sW[k * WPITCH + c0 + 4];
#pragma unroll
            for (int i = 0; i < 8; i++) {
                float hv = sH[(rbase + i) * HPITCH + k];
                acc[i][0] += hv * w0.x; acc[i][1] += hv * w0.y;
                acc[i][2] += hv * w0.z; acc[i][3] += hv * w0.w;
                acc[i][4] += hv * w1.x; acc[i][5] += hv * w1.y;
                acc[i][6] += hv * w1.z; acc[i][7] += hv * w1.w;
            }
        }
        __syncthreads();
    }
    float4 b0 = *(const float4*)(bl + c0);
    float4 b1 = *(const float4*)(bl + c0 + 4);
#pragma unroll
    for (int i = 0; i < 8; i++) {
        int row = r0 + rbase + i;
        if (row < N_NODES) {
            float4 o0 = make_float4(acc[i][0] + b0.x, acc[i][1] + b0.y,
                                    acc[i][2] + b0.z, acc[i][3] + b0.w);
            float4 o1 = make_float4(acc[i][4] + b1.x, acc[i][5] + b1.y,
                                    acc[i][6] + b1.z, acc[i][7] + b1.w);
            *(float4*)(xlo + (size_t)row * H + c0) = o0;
            *(float4*)(xlo + (size_t)row * H + c0 + 4) = o1;
        }
    }
}

// ---------------- edge kernel ----------------
// wave (64 lanes) per edge, lane handles 2 columns; 4 edge-slots per block,
// 16 consecutive edges per slot.
__global__ __launch_bounds__(256) void edge_kernel(
    const int* __restrict__ row, const int* __restrict__ col,
    const float* __restrict__ ea, const float* __restrict__ Wel,
    const float* __restrict__ bel, const float* __restrict__ xlv,
    const float* __restrict__ dis, float* __restrict__ agg) {
    __shared__ float sWe[7 * H];
    __shared__ float sbe[H];
    int t = threadIdx.x;
    for (int i = t; i < 7 * H; i += 256) sWe[i] = Wel[i];
    if (t < H) sbe[t] = bel[t];
    __syncthreads();
    int lane = t & 63, slot = t >> 6;
    int c0 = lane * 2;
    const int EPS = 16;
    long e0 = ((long)blockIdx.x * 4 + slot) * EPS;
    float be0 = sbe[c0], be1 = sbe[c0 + 1];
    for (int i = 0; i < EPS; i++) {
        long e = e0 + i;
        int r = row[e], c = col[e];
        float nrm = dis[r] * dis[c];
        const float* ep = ea + e * 7;
        float a[7];
#pragma unroll
        for (int k = 0; k < 7; k++) a[k] = ep[k];
        float m0 = be0, m1 = be1;
#pragma unroll
        for (int k = 0; k < 7; k++) {
            m0 += a[k] * sWe[k * H + c0];
            m1 += a[k] * sWe[k * H + c0 + 1];
        }
        float2 xg = *(const float2*)(xlv + (size_t)r * H + c0);
        m0 = frelu(xg.x + m0) * nrm;
        m1 = frelu(xg.y + m1) * nrm;
        unsafeAtomicAdd(&agg[(size_t)c * H + c0], m0);
        unsafeAtomicAdd(&agg[(size_t)c * H + c0 + 1], m1);
    }
}

// ---------------- BN stats + h_pre ----------------
// h_pre = agg + relu(xl + root)/deg ; accumulate per-column sum/sumsq
__global__ __launch_bounds__(256) void bn_stat(
    const float* __restrict__ agg, const float* __restrict__ xlv,
    const float* __restrict__ rootl, const float* __restrict__ invdeg,
    float* __restrict__ hpre, float* __restrict__ colsum,
    float* __restrict__ colsumsq) {
    int t = threadIdx.x;
    int cg = t & 31, rg = t >> 5;
    int c0 = cg * 4;
    float4 rt = *(const float4*)(rootl + c0);
    float4 s = make_float4(0, 0, 0, 0), sq = make_float4(0, 0, 0, 0);
    for (int rb = blockIdx.x * 8; rb < N_NODES; rb += gridDim.x * 8) {
        int rowi = rb + rg;
        if (rowi < N_NODES) {
            float id = invdeg[rowi];
            float4 a = *(const float4*)(agg + (size_t)rowi * H + c0);
            float4 x = *(const float4*)(xlv + (size_t)rowi * H + c0);
            float4 p;
            p.x = a.x + frelu(x.x + rt.x) * id;
            p.y = a.y + frelu(x.y + rt.y) * id;
            p.z = a.z + frelu(x.z + rt.z) * id;
            p.w = a.w + frelu(x.w + rt.w) * id;
            *(float4*)(hpre + (size_t)rowi * H + c0) = p;
            s.x += p.x; s.y += p.y; s.z += p.z; s.w += p.w;
            sq.x += p.x * p.x; sq.y += p.y * p.y;
            sq.z += p.z * p.z; sq.w += p.w * p.w;
        }
    }
    __shared__ float red[8][H];
    *(float4*)&red[rg][c0] = s;
    __syncthreads();
    if (rg == 0) {
        float4 tot = make_float4(0, 0, 0, 0);
#pragma unroll
        for (int g = 0; g < 8; g++) {
            float4 v = *(const float4*)&red[g][c0];
            tot.x += v.x; tot.y += v.y; tot.z += v.z; tot.w += v.w;
        }
        unsafeAtomicAdd(&colsum[c0 + 0], tot.x);
        unsafeAtomicAdd(&colsum[c0 + 1], tot.y);
        unsafeAtomicAdd(&colsum[c0 + 2], tot.z);
        unsafeAtomicAdd(&colsum[c0 + 3], tot.w);
    }
    __syncthreads();
    *(float4*)&red[rg][c0] = sq;
    __syncthreads();
    if (rg == 0) {
        float4 tot = make_float4(0, 0, 0, 0);
#pragma unroll
        for (int g = 0; g < 8; g++) {
            float4 v = *(const float4*)&red[g][c0];
            tot.x += v.x; tot.y += v.y; tot.z += v.z; tot.w += v.w;
        }
        unsafeAtomicAdd(&colsumsq[c0 + 0], tot.x);
        unsafeAtomicAdd(&colsumsq[c0 + 1], tot.y);
        unsafeAtomicAdd(&colsumsq[c0 + 2], tot.z);
        unsafeAtomicAdd(&colsumsq[c0 + 3], tot.w);
    }
}

__global__ void bn_finalize(const float* __restrict__ colsum,
                            const float* __restrict__ colsumsq,
                            const float* __restrict__ gammal,
                            const float* __restrict__ betal,
                            float* __restrict__ scale, float* __restrict__ shift) {
    int c = threadIdx.x;
    float mean = colsum[c] * (1.0f / N_NODES);
    float var = colsumsq[c] * (1.0f / N_NODES) - mean * mean;
    float s = gammal[c] * (1.0f / sqrtf(var + BN_EPS));
    scale[c] = s;
    shift[c] = betal[c] - mean * s;
}

__global__ void bn_apply(float* __restrict__ hh, const float* __restrict__ scale,
                         const float* __restrict__ shift, int dorelu) {
    size_t idx = (size_t)blockIdx.x * 256 + threadIdx.x;  // float4 index
    int c0 = ((int)idx & 31) * 4;
    float4 v = ((float4*)hh)[idx];
    float4 sc = *(const float4*)(scale + c0);
    float4 sh = *(const float4*)(shift + c0);
    v.x = v.x * sc.x + sh.x;
    v.y = v.y * sc.y + sh.y;
    v.z = v.z * sc.z + sh.z;
    v.w = v.w * sc.w + sh.w;
    if (dorelu) {
        v.x = frelu(v.x); v.y = frelu(v.y); v.z = frelu(v.z); v.w = frelu(v.w);
    }
    ((float4*)hh)[idx] = v;
}

// ---------------- pool ----------------
__global__ __launch_bounds__(256) void pool_kernel(const float* __restrict__ hh,
                                                   const int* __restrict__ batch,
                                                   float* __restrict__ pooled,
                                                   float* __restrict__ cnt) {
    int t = threadIdx.x;
    int cg = t & 31, rg = t >> 5;
    int c0 = cg * 4;
    int per = (N_NODES + gridDim.x - 1) / gridDim.x;
    int rstart = blockIdx.x * per;
    int rend = min(rstart + per, N_NODES);
    float4 acc = make_float4(0, 0, 0, 0);
    float runc = 0.0f;
    int cur = -1;
    for (int rowi = rstart + rg; rowi < rend; rowi += 8) {
        int g = batch[rowi];
        if (g != cur) {
            if (cur >= 0) {
                unsafeAtomicAdd(&pooled[(size_t)cur * H + c0 + 0], acc.x);
                unsafeAtomicAdd(&pooled[(size_t)cur * H + c0 + 1], acc.y);
                unsafeAtomicAdd(&pooled[(size_t)cur * H + c0 + 2], acc.z);
                unsafeAtomicAdd(&pooled[(size_t)cur * H + c0 + 3], acc.w);
                if (cg == 0) unsafeAtomicAdd(&cnt[cur], runc);
            }
            cur = g; acc = make_float4(0, 0, 0, 0); runc = 0.0f;
        }
        float4 v = *(const float4*)(hh + (size_t)rowi * H + c0);
        acc.x += v.x; acc.y += v.y; acc.z += v.z; acc.w += v.w;
        runc += 1.0f;
    }
    if (cur >= 0) {
        unsafeAtomicAdd(&pooled[(size_t)cur * H + c0 + 0], acc.x);
        unsafeAtomicAdd(&pooled[(size_t)cur * H + c0 + 1], acc.y);
        unsafeAtomicAdd(&pooled[(size_t)cur * H + c0 + 2], acc.z);
        unsafeAtomicAdd(&pooled[(size_t)cur * H + c0 + 3], acc.w);
        if (cg == 0) unsafeAtomicAdd(&cnt[cur], runc);
    }
}

// ---------------- final: out = (pooled/cnt) @ Wout + bout ----------------
__global__ __launch_bounds__(128) void final_gemm(const float* __restrict__ pooled,
                                                  const float* __restrict__ cnt,
                                                  const float* __restrict__ Wout,
                                                  const float* __restrict__ bout,
                                                  float* __restrict__ out) {
    __shared__ float sh[H];
    int g = blockIdx.x;
    int o = threadIdx.x;
    float c = fmaxf(cnt[g], 1.0f);
    sh[o] = pooled[(size_t)g * H + o] / c;
    __syncthreads();
    float acc = bout[o];
#pragma unroll 8
    for (int k = 0; k < H; k++) acc += sh[k] * Wout[(size_t)k * OUT_F + o];
    out[(size_t)g * OUT_F + o] = acc;
}

extern "C" void kernel_launch(void* const* d_in, const int* in_sizes, int n_in,
                              void* d_out, int out_size, void* d_ws, size_t ws_size,
                              hipStream_t stream) {
    const int*   x     = (const int*)d_in[0];
    const int*   ei    = (const int*)d_in[1];
    const float* ea    = (const float*)d_in[2];
    const int*   batch = (const int*)d_in[3];
    const float* nemb  = (const float*)d_in[4];
    const float* W     = (const float*)d_in[5];
    const float* b     = (const float*)d_in[6];
    const float* We    = (const float*)d_in[7];
    const float* be    = (const float*)d_in[8];
    const float* root  = (const float*)d_in[9];
    const float* gamma = (const float*)d_in[10];
    const float* beta  = (const float*)d_in[11];
    const float* Wout  = (const float*)d_in[12];
    const float* bout  = (const float*)d_in[13];
    float* out = (float*)d_out;

    const int* erow = ei;
    const int* ecol = ei + N_EDGES;

    float* ws = (float*)d_ws;
    size_t NH = (size_t)N_NODES * H;
    float* h      = ws;
    float* xl     = h + NH;
    float* agg    = xl + NH;
    float* deg    = agg + NH;
    float* dis    = deg + N_NODES;
    float* invdeg = dis + N_NODES;
    float* colsum   = invdeg + N_NODES;        // 128
    float* colsumsq = colsum + H;              // 128
    float* scale    = colsumsq + H;            // 128
    float* shift    = scale + H;               // 128
    float* pooled   = shift + H;               // G*H
    float* cnt      = pooled + (size_t)G_GRAPHS * H;  // G

    // degree
    hipLaunchKernelGGL(init_deg, dim3((N_NODES + 255) / 256), dim3(256), 0, stream, deg);
    hipLaunchKernelGGL(count_deg, dim3(N_EDGES / 256), dim3(256), 0, stream, erow, deg);
    hipLaunchKernelGGL(finish_deg, dim3((N_NODES + 255) / 256), dim3(256), 0, stream,
                       deg, dis, invdeg);
    // h init
    hipLaunchKernelGGL(init_h, dim3((unsigned)(NH / 4 / 256)), dim3(256), 0, stream,
                       x, nemb, h);

    for (int l = 0; l < L_LAYERS; l++) {
        hipLaunchKernelGGL(gemm_xl, dim3((N_NODES + 127) / 128), dim3(256), 0, stream,
                           h, W + (size_t)l * H * H, b + (size_t)l * H, xl);
        hipMemsetAsync(agg, 0, NH * sizeof(float), stream);
        hipMemsetAsync(colsum, 0, 2 * H * sizeof(float), stream);
        hipLaunchKernelGGL(edge_kernel, dim3(N_EDGES / 64), dim3(256), 0, stream,
                           erow, ecol, ea, We + (size_t)l * 7 * H, be + (size_t)l * H,
                           xl, dis, agg);
        hipLaunchKernelGGL(bn_stat, dim3(512), dim3(256), 0, stream,
                           agg, xl, root + (size_t)l * H, invdeg, h, colsum, colsumsq);
        hipLaunchKernelGGL(bn_finalize, dim3(1), dim3(H), 0, stream,
                           colsum, colsumsq, gamma + (size_t)l * H, beta + (size_t)l * H,
                           scale, shift);
        hipLaunchKernelGGL(bn_apply, dim3((unsigned)(NH / 4 / 256)), dim3(256), 0, stream,
                           h, scale, shift, (l < L_LAYERS - 1) ? 1 : 0);
    }

    hipMemsetAsync(pooled, 0, ((size_t)G_GRAPHS * H + G_GRAPHS) * sizeof(float), stream);
    hipLaunchKernelGGL(pool_kernel, dim3(256), dim3(256), 0, stream, h, batch, pooled, cnt);
    hipLaunchKernelGGL(final_gemm, dim3(G_GRAPHS), dim3(OUT_F), 0, stream,
                       pooled, cnt, Wout, bout, out);
}

// Round 2
// 2243.637 us; speedup vs baseline: 3.2921x; 3.2921x over previous
//
#include <hip/hip_runtime.h>
#include <cstdint>
#include <cstddef>

#define N_NODES 100000
#define N_EDGES 1600000
#define H 128
#define L_LAYERS 5
#define G_GRAPHS 128
#define OUT_F 128
#define BN_EPS 1e-5f

__device__ __forceinline__ float frelu(float x) { return fmaxf(x, 0.0f); }

// ================= preprocessing =================

// histogram of row (for deg) and col (for CSR)
__global__ void count_kernel(const int* __restrict__ erow, const int* __restrict__ ecol,
                             int* __restrict__ degcnt, int* __restrict__ hist) {
    int e = blockIdx.x * 256 + threadIdx.x;  // E divisible by 256
    atomicAdd(&degcnt[erow[e]], 1);
    atomicAdd(&hist[ecol[e]], 1);
}

__global__ void finish_deg(const int* __restrict__ degcnt, float* __restrict__ dis,
                           float* __restrict__ invdeg) {
    int i = blockIdx.x * 256 + threadIdx.x;
    if (i < N_NODES) {
        float d = (float)degcnt[i] + 1.0f;
        dis[i] = rsqrtf(d);
        invdeg[i] = 1.0f / d;
    }
}

// exclusive scan of hist[0..N) -> rowptr[0..N], cursor copy. Single block, 1024 thr.
__global__ __launch_bounds__(1024) void scan_hist(const int* __restrict__ hist,
                                                  int* __restrict__ rowptr,
                                                  int* __restrict__ cursor) {
    __shared__ int part[1024];
    const int CH = 98;  // 1024*98 = 100352 >= 100000
    int t = threadIdx.x;
    int base = t * CH;
    int s = 0;
    for (int i = 0; i < CH; i++) {
        int g = base + i;
        if (g < N_NODES) s += hist[g];
    }
    part[t] = s;
    __syncthreads();
    // inclusive scan (Hillis-Steele)
    for (int off = 1; off < 1024; off <<= 1) {
        int v = (t >= off) ? part[t - off] : 0;
        __syncthreads();
        part[t] += v;
        __syncthreads();
    }
    int pre = (t == 0) ? 0 : part[t - 1];
    for (int i = 0; i < CH; i++) {
        int g = base + i;
        if (g < N_NODES) {
            rowptr[g] = pre;
            cursor[g] = pre;
            pre += hist[g];
        }
    }
    if (t == 1023) rowptr[N_NODES] = N_EDGES;
}

// permute edge payloads into col-sorted order: ea8[j*8] = {ea[0..6], bitcast(row)}
__global__ void scatter_kernel(const int* __restrict__ erow, const int* __restrict__ ecol,
                               const float* __restrict__ ea, int* __restrict__ cursor,
                               float* __restrict__ ea8) {
    int e = blockIdx.x * 256 + threadIdx.x;
    int c = ecol[e];
    int r = erow[e];
    int pos = atomicAdd(&cursor[c], 1);
    const float* p = ea + (size_t)e * 7;
    float a0 = p[0], a1 = p[1], a2 = p[2], a3 = p[3], a4 = p[4], a5 = p[5], a6 = p[6];
    float* dst = ea8 + (size_t)pos * 8;
    float4 v0 = make_float4(a0, a1, a2, a3);
    float4 v1 = make_float4(a4, a5, a6, __int_as_float(r));
    *(float4*)dst = v0;
    *(float4*)(dst + 4) = v1;
}

// ================= xl = act(h) @ W + b =================
// mode 0: h = node_emb[x[row]] (first layer); mode 1: h = relu(hpre*scale+shift)
__global__ __launch_bounds__(256) void gemm_xl(const float* __restrict__ hsrc,
                                               const int* __restrict__ xidx,
                                               const float* __restrict__ nemb,
                                               const float* __restrict__ scale,
                                               const float* __restrict__ shift,
                                               const float* __restrict__ Wl,
                                               const float* __restrict__ bl,
                                               float* __restrict__ xlo, int mode) {
    constexpr int KC = 32;
    constexpr int HPITCH = 33;
    constexpr int WPITCH = 132;
    __shared__ float sH[128 * HPITCH];
    __shared__ float sW[KC * WPITCH];
    int t = threadIdx.x;
    int tx = t & 15, ty = t >> 4;
    int r0 = blockIdx.x * 128;
    int c0 = tx * 8;
    int rbase = ty * 8;
    float acc[8][8];
#pragma unroll
    for (int i = 0; i < 8; i++)
#pragma unroll
        for (int j = 0; j < 8; j++) acc[i][j] = 0.0f;

    for (int kc = 0; kc < H; kc += KC) {
        for (int idx = t; idx < 1024; idx += 256) {
            int rowi = idx >> 3;
            int kg = idx & 7;
            int gr = r0 + rowi; if (gr > N_NODES - 1) gr = N_NODES - 1;
            float4 v;
            if (mode == 0) {
                int xv = xidx[gr];
                v = *(const float4*)(nemb + (size_t)xv * H + kc + kg * 4);
            } else {
                v = *(const float4*)(hsrc + (size_t)gr * H + kc + kg * 4);
                float4 sc = *(const float4*)(scale + kc + kg * 4);
                float4 sh = *(const float4*)(shift + kc + kg * 4);
                v.x = frelu(v.x * sc.x + sh.x);
                v.y = frelu(v.y * sc.y + sh.y);
                v.z = frelu(v.z * sc.z + sh.z);
                v.w = frelu(v.w * sc.w + sh.w);
            }
            float* d = &sH[rowi * HPITCH + kg * 4];
            d[0] = v.x; d[1] = v.y; d[2] = v.z; d[3] = v.w;
        }
        for (int idx = t; idx < 1024; idx += 256) {
            int k = idx >> 5;
            int cg = idx & 31;
            *(float4*)&sW[k * WPITCH + cg * 4] =
                *(const float4*)(Wl + (size_t)(kc + k) * H + cg * 4);
        }
        __syncthreads();
#pragma unroll 4
        for (int k = 0; k < KC; k++) {
            float4 w0 = *(const float4*)&sW[k * WPITCH + c0];
            float4 w1 = *(const float4*)&sW[k * WPITCH + c0 + 4];
#pragma unroll
            for (int i = 0; i < 8; i++) {
                float hv = sH[(rbase + i) * HPITCH + k];
                acc[i][0] += hv * w0.x; acc[i][1] += hv * w0.y;
                acc[i][2] += hv * w0.z; acc[i][3] += hv * w0.w;
                acc[i][4] += hv * w1.x; acc[i][5] += hv * w1.y;
                acc[i][6] += hv * w1.z; acc[i][7] += hv * w1.w;
            }
        }
        __syncthreads();
    }
    float4 b0 = *(const float4*)(bl + c0);
    float4 b1 = *(const float4*)(bl + c0 + 4);
#pragma unroll
    for (int i = 0; i < 8; i++) {
        int row = r0 + rbase + i;
        if (row < N_NODES) {
            float4 o0 = make_float4(acc[i][0] + b0.x, acc[i][1] + b0.y,
                                    acc[i][2] + b0.z, acc[i][3] + b0.w);
            float4 o1 = make_float4(acc[i][4] + b1.x, acc[i][5] + b1.y,
                                    acc[i][6] + b1.z, acc[i][7] + b1.w);
            *(float4*)(xlo + (size_t)row * H + c0) = o0;
            *(float4*)(xlo + (size_t)row * H + c0 + 4) = o1;
        }
    }
}

// ================= gather aggregation + BN stats =================
// wave per node (persistent, strided); lane owns cols {2*lane, 2*lane+1}.
// hpre[n] = sum_{e: col==n} norm*relu(xl[row]+eMLP) + relu(xl[n]+root)/deg[n]
__global__ __launch_bounds__(256) void agg_kernel(
    const int* __restrict__ rowptr, const float* __restrict__ ea8,
    const float* __restrict__ xl, const float* __restrict__ dis,
    const float* __restrict__ invdeg, const float* __restrict__ rootl,
    const float* __restrict__ Wel, const float* __restrict__ bel,
    float* __restrict__ hpre, float* __restrict__ colsum,
    float* __restrict__ colsumsq) {
    int t = threadIdx.x;
    int lane = t & 63, wv = t >> 6;
    int c0 = lane * 2;
    // per-lane weights in registers
    float w00 = Wel[0 * H + c0], w01 = Wel[0 * H + c0 + 1];
    float w10 = Wel[1 * H + c0], w11 = Wel[1 * H + c0 + 1];
    float w20 = Wel[2 * H + c0], w21 = Wel[2 * H + c0 + 1];
    float w30 = Wel[3 * H + c0], w31 = Wel[3 * H + c0 + 1];
    float w40 = Wel[4 * H + c0], w41 = Wel[4 * H + c0 + 1];
    float w50 = Wel[5 * H + c0], w51 = Wel[5 * H + c0 + 1];
    float w60 = Wel[6 * H + c0], w61 = Wel[6 * H + c0 + 1];
    float be0 = bel[c0], be1 = bel[c0 + 1];
    float rt0 = rootl[c0], rt1 = rootl[c0 + 1];
    float s0 = 0, s1 = 0, q0 = 0, q1 = 0;

    for (int n = blockIdx.x * 4 + wv; n < N_NODES; n += gridDim.x * 4) {
        int jb = rowptr[n], je = rowptr[n + 1];
        float dn = dis[n];
        float a0 = 0, a1 = 0;
        for (int j = jb; j < je; j++) {
            const float* ep = ea8 + (size_t)j * 8;
            float4 v0 = *(const float4*)ep;
            float4 v1 = *(const float4*)(ep + 4);
            int r = __float_as_int(v1.w);
            float nrm = dis[r] * dn;
            float2 xg = *(const float2*)(xl + (size_t)r * H + c0);
            float m0 = be0, m1 = be1;
            m0 = fmaf(v0.x, w00, m0); m1 = fmaf(v0.x, w01, m1);
            m0 = fmaf(v0.y, w10, m0); m1 = fmaf(v0.y, w11, m1);
            m0 = fmaf(v0.z, w20, m0); m1 = fmaf(v0.z, w21, m1);
            m0 = fmaf(v0.w, w30, m0); m1 = fmaf(v0.w, w31, m1);
            m0 = fmaf(v1.x, w40, m0); m1 = fmaf(v1.x, w41, m1);
            m0 = fmaf(v1.y, w50, m0); m1 = fmaf(v1.y, w51, m1);
            m0 = fmaf(v1.z, w60, m0); m1 = fmaf(v1.z, w61, m1);
            a0 = fmaf(frelu(xg.x + m0), nrm, a0);
            a1 = fmaf(frelu(xg.y + m1), nrm, a1);
        }
        float2 xn = *(const float2*)(xl + (size_t)n * H + c0);
        float id = invdeg[n];
        float p0 = a0 + frelu(xn.x + rt0) * id;
        float p1 = a1 + frelu(xn.y + rt1) * id;
        float2 pv = make_float2(p0, p1);
        *(float2*)(hpre + (size_t)n * H + c0) = pv;
        s0 += p0; s1 += p1;
        q0 = fmaf(p0, p0, q0); q1 = fmaf(p1, p1, q1);
    }

    // block-level reduce of colsum/colsumsq, then one atomic per col per block
    __shared__ float red[4][H];
    red[wv][c0] = s0; red[wv][c0 + 1] = s1;
    __syncthreads();
    if (wv == 0) {
        float t0 = red[0][c0] + red[1][c0] + red[2][c0] + red[3][c0];
        float t1 = red[0][c0 + 1] + red[1][c0 + 1] + red[2][c0 + 1] + red[3][c0 + 1];
        unsafeAtomicAdd(&colsum[c0], t0);
        unsafeAtomicAdd(&colsum[c0 + 1], t1);
    }
    __syncthreads();
    red[wv][c0] = q0; red[wv][c0 + 1] = q1;
    __syncthreads();
    if (wv == 0) {
        float t0 = red[0][c0] + red[1][c0] + red[2][c0] + red[3][c0];
        float t1 = red[0][c0 + 1] + red[1][c0 + 1] + red[2][c0 + 1] + red[3][c0 + 1];
        unsafeAtomicAdd(&colsumsq[c0], t0);
        unsafeAtomicAdd(&colsumsq[c0 + 1], t1);
    }
}

__global__ void bn_finalize(const float* __restrict__ colsum,
                            const float* __restrict__ colsumsq,
                            const float* __restrict__ gammal,
                            const float* __restrict__ betal,
                            float* __restrict__ scale, float* __restrict__ shift) {
    int c = threadIdx.x;
    float mean = colsum[c] * (1.0f / N_NODES);
    float var = colsumsq[c] * (1.0f / N_NODES) - mean * mean;
    float s = gammal[c] * rsqrtf(var + BN_EPS);
    scale[c] = s;
    shift[c] = betal[c] - mean * s;
}

// ================= pool (applies final BN, no relu) =================
__global__ __launch_bounds__(256) void pool_kernel(const float* __restrict__ hh,
                                                   const int* __restrict__ batch,
                                                   const float* __restrict__ scale,
                                                   const float* __restrict__ shift,
                                                   float* __restrict__ pooled,
                                                   float* __restrict__ cnt) {
    int t = threadIdx.x;
    int cg = t & 31, rg = t >> 5;
    int c0 = cg * 4;
    float4 sc = *(const float4*)(scale + c0);
    float4 sh = *(const float4*)(shift + c0);
    int per = (N_NODES + gridDim.x - 1) / gridDim.x;
    int rstart = blockIdx.x * per;
    int rend = min(rstart + per, N_NODES);
    float4 acc = make_float4(0, 0, 0, 0);
    float runc = 0.0f;
    int cur = -1;
    for (int rowi = rstart + rg; rowi < rend; rowi += 8) {
        int g = batch[rowi];
        if (g != cur) {
            if (cur >= 0) {
                unsafeAtomicAdd(&pooled[(size_t)cur * H + c0 + 0], acc.x);
                unsafeAtomicAdd(&pooled[(size_t)cur * H + c0 + 1], acc.y);
                unsafeAtomicAdd(&pooled[(size_t)cur * H + c0 + 2], acc.z);
                unsafeAtomicAdd(&pooled[(size_t)cur * H + c0 + 3], acc.w);
                if (cg == 0) unsafeAtomicAdd(&cnt[cur], runc);
            }
            cur = g; acc = make_float4(0, 0, 0, 0); runc = 0.0f;
        }
        float4 v = *(const float4*)(hh + (size_t)rowi * H + c0);
        acc.x += v.x * sc.x + sh.x;
        acc.y += v.y * sc.y + sh.y;
        acc.z += v.z * sc.z + sh.z;
        acc.w += v.w * sc.w + sh.w;
        runc += 1.0f;
    }
    if (cur >= 0) {
        unsafeAtomicAdd(&pooled[(size_t)cur * H + c0 + 0], acc.x);
        unsafeAtomicAdd(&pooled[(size_t)cur * H + c0 + 1], acc.y);
        unsafeAtomicAdd(&pooled[(size_t)cur * H + c0 + 2], acc.z);
        unsafeAtomicAdd(&pooled[(size_t)cur * H + c0 + 3], acc.w);
        if (cg == 0) unsafeAtomicAdd(&cnt[cur], runc);
    }
}

__global__ __launch_bounds__(128) void final_gemm(const float* __restrict__ pooled,
                                                  const float* __restrict__ cnt,
                                                  const float* __restrict__ Wout,
                                                  const float* __restrict__ bout,
                                                  float* __restrict__ out) {
    __shared__ float sh[H];
    int g = blockIdx.x;
    int o = threadIdx.x;
    float c = fmaxf(cnt[g], 1.0f);
    sh[o] = pooled[(size_t)g * H + o] / c;
    __syncthreads();
    float acc = bout[o];
#pragma unroll 8
    for (int k = 0; k < H; k++) acc += sh[k] * Wout[(size_t)k * OUT_F + o];
    out[(size_t)g * OUT_F + o] = acc;
}

extern "C" void kernel_launch(void* const* d_in, const int* in_sizes, int n_in,
                              void* d_out, int out_size, void* d_ws, size_t ws_size,
                              hipStream_t stream) {
    const int*   x     = (const int*)d_in[0];
    const int*   ei    = (const int*)d_in[1];
    const float* ea    = (const float*)d_in[2];
    const int*   batch = (const int*)d_in[3];
    const float* nemb  = (const float*)d_in[4];
    const float* W     = (const float*)d_in[5];
    const float* b     = (const float*)d_in[6];
    const float* We    = (const float*)d_in[7];
    const float* be    = (const float*)d_in[8];
    const float* root  = (const float*)d_in[9];
    const float* gamma = (const float*)d_in[10];
    const float* beta  = (const float*)d_in[11];
    const float* Wout  = (const float*)d_in[12];
    const float* bout  = (const float*)d_in[13];
    float* out = (float*)d_out;

    const int* erow = ei;
    const int* ecol = ei + N_EDGES;

    float* ws = (float*)d_ws;
    size_t NH = (size_t)N_NODES * H;
    float* ea8    = ws;                       // E*8 = 12.8M floats
    float* hpre   = ea8 + (size_t)N_EDGES * 8;
    float* xl     = hpre + NH;
    int*   rowptr = (int*)(xl + NH);          // N+1 (+pad)
    float* dis    = (float*)(rowptr + N_NODES + 4);
    float* invdeg = dis + N_NODES;
    float* colsum   = invdeg + N_NODES;       // 128
    float* colsumsq = colsum + H;             // 128
    float* scale    = colsumsq + H;           // 128
    float* shift    = scale + H;              // 128
    float* pooled   = shift + H;              // G*H
    float* cnt      = pooled + (size_t)G_GRAPHS * H;  // G

    // preprocessing temps alias into hpre region (hpre first written after scatter)
    int* degcnt = (int*)hpre;
    int* hist   = degcnt + N_NODES;
    int* cursor = hist + N_NODES;

    hipMemsetAsync(degcnt, 0, 2 * N_NODES * sizeof(int), stream);
    hipLaunchKernelGGL(count_kernel, dim3(N_EDGES / 256), dim3(256), 0, stream,
                       erow, ecol, degcnt, hist);
    hipLaunchKernelGGL(finish_deg, dim3((N_NODES + 255) / 256), dim3(256), 0, stream,
                       degcnt, dis, invdeg);
    hipLaunchKernelGGL(scan_hist, dim3(1), dim3(1024), 0, stream, hist, rowptr, cursor);
    hipLaunchKernelGGL(scatter_kernel, dim3(N_EDGES / 256), dim3(256), 0, stream,
                       erow, ecol, ea, cursor, ea8);

    for (int l = 0; l < L_LAYERS; l++) {
        hipLaunchKernelGGL(gemm_xl, dim3((N_NODES + 127) / 128), dim3(256), 0, stream,
                           hpre, x, nemb, scale, shift,
                           W + (size_t)l * H * H, b + (size_t)l * H, xl,
                           (l == 0) ? 0 : 1);
        hipMemsetAsync(colsum, 0, 2 * H * sizeof(float), stream);
        hipLaunchKernelGGL(agg_kernel, dim3(2048), dim3(256), 0, stream,
                           rowptr, ea8, xl, dis, invdeg,
                           root + (size_t)l * H, We + (size_t)l * 7 * H, be + (size_t)l * H,
                           hpre, colsum, colsumsq);
        hipLaunchKernelGGL(bn_finalize, dim3(1), dim3(H), 0, stream,
                           colsum, colsumsq, gamma + (size_t)l * H, beta + (size_t)l * H,
                           scale, shift);
    }

    hipMemsetAsync(pooled, 0, ((size_t)G_GRAPHS * H + G_GRAPHS) * sizeof(float), stream);
    hipLaunchKernelGGL(pool_kernel, dim3(256), dim3(256), 0, stream,
                       hpre, batch, scale, shift, pooled, cnt);
    hipLaunchKernelGGL(final_gemm, dim3(G_GRAPHS), dim3(OUT_F), 0, stream,
                       pooled, cnt, Wout, bout, out);
}

// Round 3
// 2046.089 us; speedup vs baseline: 3.6099x; 1.0965x over previous
//
#include <hip/hip_runtime.h>
#include <cstdint>
#include <cstddef>

#define N_NODES 100000
#define N_EDGES 1600000
#define H 128
#define L_LAYERS 5
#define G_GRAPHS 128
#define OUT_F 128
#define BN_EPS 1e-5f

__device__ __forceinline__ float frelu(float x) { return fmaxf(x, 0.0f); }

// ================= preprocessing =================

// histogram of row (for deg) and col (for CSR)
__global__ void count_kernel(const int* __restrict__ erow, const int* __restrict__ ecol,
                             int* __restrict__ degcnt, int* __restrict__ hist) {
    int e = blockIdx.x * 256 + threadIdx.x;  // E divisible by 256
    atomicAdd(&degcnt[erow[e]], 1);
    atomicAdd(&hist[ecol[e]], 1);
}

__global__ void finish_deg(const int* __restrict__ degcnt, float* __restrict__ dis,
                           float* __restrict__ invdeg) {
    int i = blockIdx.x * 256 + threadIdx.x;
    if (i < N_NODES) {
        float d = (float)degcnt[i] + 1.0f;
        dis[i] = rsqrtf(d);
        invdeg[i] = 1.0f / d;
    }
}

// exclusive scan of hist[0..N) -> rowptr[0..N], cursor copy. Single block, 1024 thr.
__global__ __launch_bounds__(1024) void scan_hist(const int* __restrict__ hist,
                                                  int* __restrict__ rowptr,
                                                  int* __restrict__ cursor) {
    __shared__ int part[1024];
    const int CH = 98;  // 1024*98 = 100352 >= 100000
    int t = threadIdx.x;
    int base = t * CH;
    int s = 0;
    for (int i = 0; i < CH; i++) {
        int g = base + i;
        if (g < N_NODES) s += hist[g];
    }
    part[t] = s;
    __syncthreads();
    // inclusive scan (Hillis-Steele)
    for (int off = 1; off < 1024; off <<= 1) {
        int v = (t >= off) ? part[t - off] : 0;
        __syncthreads();
        part[t] += v;
        __syncthreads();
    }
    int pre = (t == 0) ? 0 : part[t - 1];
    for (int i = 0; i < CH; i++) {
        int g = base + i;
        if (g < N_NODES) {
            rowptr[g] = pre;
            cursor[g] = pre;
            pre += hist[g];
        }
    }
    if (t == 1023) rowptr[N_NODES] = N_EDGES;
}

// permute edge payloads into col-sorted order:
//   ea8[pos*8] = {ea[0..6], norm}   rows[pos] = row
// norm = dis[row]*dis[col] is layer-invariant -> hoisted out of the hot loop.
__global__ void scatter_kernel(const int* __restrict__ erow, const int* __restrict__ ecol,
                               const float* __restrict__ ea, const float* __restrict__ dis,
                               int* __restrict__ cursor,
                               float* __restrict__ ea8, int* __restrict__ rows) {
    int e = blockIdx.x * 256 + threadIdx.x;
    int c = ecol[e];
    int r = erow[e];
    float nrm = dis[r] * dis[c];
    int pos = atomicAdd(&cursor[c], 1);
    const float* p = ea + (size_t)e * 7;
    float a0 = p[0], a1 = p[1], a2 = p[2], a3 = p[3], a4 = p[4], a5 = p[5], a6 = p[6];
    float* dst = ea8 + (size_t)pos * 8;
    *(float4*)dst = make_float4(a0, a1, a2, a3);
    *(float4*)(dst + 4) = make_float4(a4, a5, a6, nrm);
    rows[pos] = r;
}

// ================= xl = act(h) @ W + b =================
// mode 0: h = node_emb[x[row]] (first layer); mode 1: h = relu(hpre*scale+shift)
__global__ __launch_bounds__(256) void gemm_xl(const float* __restrict__ hsrc,
                                               const int* __restrict__ xidx,
                                               const float* __restrict__ nemb,
                                               const float* __restrict__ scale,
                                               const float* __restrict__ shift,
                                               const float* __restrict__ Wl,
                                               const float* __restrict__ bl,
                                               float* __restrict__ xlo, int mode) {
    constexpr int KC = 32;
    constexpr int HPITCH = 33;
    constexpr int WPITCH = 132;
    __shared__ float sH[128 * HPITCH];
    __shared__ float sW[KC * WPITCH];
    int t = threadIdx.x;
    int tx = t & 15, ty = t >> 4;
    int r0 = blockIdx.x * 128;
    int c0 = tx * 8;
    int rbase = ty * 8;
    float acc[8][8];
#pragma unroll
    for (int i = 0; i < 8; i++)
#pragma unroll
        for (int j = 0; j < 8; j++) acc[i][j] = 0.0f;

    for (int kc = 0; kc < H; kc += KC) {
        for (int idx = t; idx < 1024; idx += 256) {
            int rowi = idx >> 3;
            int kg = idx & 7;
            int gr = r0 + rowi; if (gr > N_NODES - 1) gr = N_NODES - 1;
            float4 v;
            if (mode == 0) {
                int xv = xidx[gr];
                v = *(const float4*)(nemb + (size_t)xv * H + kc + kg * 4);
            } else {
                v = *(const float4*)(hsrc + (size_t)gr * H + kc + kg * 4);
                float4 sc = *(const float4*)(scale + kc + kg * 4);
                float4 sh = *(const float4*)(shift + kc + kg * 4);
                v.x = frelu(v.x * sc.x + sh.x);
                v.y = frelu(v.y * sc.y + sh.y);
                v.z = frelu(v.z * sc.z + sh.z);
                v.w = frelu(v.w * sc.w + sh.w);
            }
            float* d = &sH[rowi * HPITCH + kg * 4];
            d[0] = v.x; d[1] = v.y; d[2] = v.z; d[3] = v.w;
        }
        for (int idx = t; idx < 1024; idx += 256) {
            int k = idx >> 5;
            int cg = idx & 31;
            *(float4*)&sW[k * WPITCH + cg * 4] =
                *(const float4*)(Wl + (size_t)(kc + k) * H + cg * 4);
        }
        __syncthreads();
#pragma unroll 4
        for (int k = 0; k < KC; k++) {
            float4 w0 = *(const float4*)&sW[k * WPITCH + c0];
            float4 w1 = *(const float4*)&sW[k * WPITCH + c0 + 4];
#pragma unroll
            for (int i = 0; i < 8; i++) {
                float hv = sH[(rbase + i) * HPITCH + k];
                acc[i][0] += hv * w0.x; acc[i][1] += hv * w0.y;
                acc[i][2] += hv * w0.z; acc[i][3] += hv * w0.w;
                acc[i][4] += hv * w1.x; acc[i][5] += hv * w1.y;
                acc[i][6] += hv * w1.z; acc[i][7] += hv * w1.w;
            }
        }
        __syncthreads();
    }
    float4 b0 = *(const float4*)(bl + c0);
    float4 b1 = *(const float4*)(bl + c0 + 4);
#pragma unroll
    for (int i = 0; i < 8; i++) {
        int row = r0 + rbase + i;
        if (row < N_NODES) {
            float4 o0 = make_float4(acc[i][0] + b0.x, acc[i][1] + b0.y,
                                    acc[i][2] + b0.z, acc[i][3] + b0.w);
            float4 o1 = make_float4(acc[i][4] + b1.x, acc[i][5] + b1.y,
                                    acc[i][6] + b1.z, acc[i][7] + b1.w);
            *(float4*)(xlo + (size_t)row * H + c0) = o0;
            *(float4*)(xlo + (size_t)row * H + c0 + 4) = o1;
        }
    }
}

// ================= gather aggregation + BN stats =================
// wave per node (persistent, strided); lane owns cols {2*lane, 2*lane+1}.
// hpre[n] = sum_{e: col==n} norm*relu(xl[row]+eMLP) + relu(xl[n]+root)/deg[n]
// 4-wide edge unroll for memory-level parallelism.
__global__ __launch_bounds__(256) void agg_kernel(
    const int* __restrict__ rowptr, const float* __restrict__ ea8,
    const int* __restrict__ rows, const float* __restrict__ xl,
    const float* __restrict__ invdeg, const float* __restrict__ rootl,
    const float* __restrict__ Wel, const float* __restrict__ bel,
    float* __restrict__ hpre, float* __restrict__ colsum,
    float* __restrict__ colsumsq) {
    int t = threadIdx.x;
    int lane = t & 63, wv = t >> 6;
    int c0 = lane * 2;
    float w00 = Wel[0 * H + c0], w01 = Wel[0 * H + c0 + 1];
    float w10 = Wel[1 * H + c0], w11 = Wel[1 * H + c0 + 1];
    float w20 = Wel[2 * H + c0], w21 = Wel[2 * H + c0 + 1];
    float w30 = Wel[3 * H + c0], w31 = Wel[3 * H + c0 + 1];
    float w40 = Wel[4 * H + c0], w41 = Wel[4 * H + c0 + 1];
    float w50 = Wel[5 * H + c0], w51 = Wel[5 * H + c0 + 1];
    float w60 = Wel[6 * H + c0], w61 = Wel[6 * H + c0 + 1];
    float be0 = bel[c0], be1 = bel[c0 + 1];
    float rt0 = rootl[c0], rt1 = rootl[c0 + 1];
    float s0 = 0, s1 = 0, q0 = 0, q1 = 0;

#define EDGE_BODY(JJ)                                                        \
    {                                                                        \
        int r_ = rows[(JJ)];                                                 \
        const float* ep_ = ea8 + (size_t)(JJ) * 8;                           \
        float4 v0_ = *(const float4*)ep_;                                    \
        float4 v1_ = *(const float4*)(ep_ + 4);                              \
        float2 xg_ = *(const float2*)(xl + (size_t)r_ * H + c0);             \
        float m0_ = be0, m1_ = be1;                                          \
        m0_ = fmaf(v0_.x, w00, m0_); m1_ = fmaf(v0_.x, w01, m1_);            \
        m0_ = fmaf(v0_.y, w10, m0_); m1_ = fmaf(v0_.y, w11, m1_);            \
        m0_ = fmaf(v0_.z, w20, m0_); m1_ = fmaf(v0_.z, w21, m1_);            \
        m0_ = fmaf(v0_.w, w30, m0_); m1_ = fmaf(v0_.w, w31, m1_);            \
        m0_ = fmaf(v1_.x, w40, m0_); m1_ = fmaf(v1_.x, w41, m1_);            \
        m0_ = fmaf(v1_.y, w50, m0_); m1_ = fmaf(v1_.y, w51, m1_);            \
        m0_ = fmaf(v1_.z, w60, m0_); m1_ = fmaf(v1_.z, w61, m1_);            \
        a0 = fmaf(frelu(xg_.x + m0_), v1_.w, a0);                            \
        a1 = fmaf(frelu(xg_.y + m1_), v1_.w, a1);                            \
    }

    for (int n = blockIdx.x * 4 + wv; n < N_NODES; n += gridDim.x * 4) {
        int jb = rowptr[n], je = rowptr[n + 1];
        float a0 = 0, a1 = 0;
        int j = jb;
        for (; j + 4 <= je; j += 4) {
            EDGE_BODY(j);
            EDGE_BODY(j + 1);
            EDGE_BODY(j + 2);
            EDGE_BODY(j + 3);
        }
        for (; j < je; j++) EDGE_BODY(j);
        float2 xn = *(const float2*)(xl + (size_t)n * H + c0);
        float id = invdeg[n];
        float p0 = a0 + frelu(xn.x + rt0) * id;
        float p1 = a1 + frelu(xn.y + rt1) * id;
        *(float2*)(hpre + (size_t)n * H + c0) = make_float2(p0, p1);
        s0 += p0; s1 += p1;
        q0 = fmaf(p0, p0, q0); q1 = fmaf(p1, p1, q1);
    }
#undef EDGE_BODY

    __shared__ float red[4][H];
    red[wv][c0] = s0; red[wv][c0 + 1] = s1;
    __syncthreads();
    if (wv == 0) {
        float t0 = red[0][c0] + red[1][c0] + red[2][c0] + red[3][c0];
        float t1 = red[0][c0 + 1] + red[1][c0 + 1] + red[2][c0 + 1] + red[3][c0 + 1];
        unsafeAtomicAdd(&colsum[c0], t0);
        unsafeAtomicAdd(&colsum[c0 + 1], t1);
    }
    __syncthreads();
    red[wv][c0] = q0; red[wv][c0 + 1] = q1;
    __syncthreads();
    if (wv == 0) {
        float t0 = red[0][c0] + red[1][c0] + red[2][c0] + red[3][c0];
        float t1 = red[0][c0 + 1] + red[1][c0 + 1] + red[2][c0 + 1] + red[3][c0 + 1];
        unsafeAtomicAdd(&colsumsq[c0], t0);
        unsafeAtomicAdd(&colsumsq[c0 + 1], t1);
    }
}

__global__ void bn_finalize(const float* __restrict__ colsum,
                            const float* __restrict__ colsumsq,
                            const float* __restrict__ gammal,
                            const float* __restrict__ betal,
                            float* __restrict__ scale, float* __restrict__ shift) {
    int c = threadIdx.x;
    float mean = colsum[c] * (1.0f / N_NODES);
    float var = colsumsq[c] * (1.0f / N_NODES) - mean * mean;
    float s = gammal[c] * rsqrtf(var + BN_EPS);
    scale[c] = s;
    shift[c] = betal[c] - mean * s;
}

// ================= pool (applies final BN, no relu) =================
__global__ __launch_bounds__(256) void pool_kernel(const float* __restrict__ hh,
                                                   const int* __restrict__ batch,
                                                   const float* __restrict__ scale,
                                                   const float* __restrict__ shift,
                                                   float* __restrict__ pooled,
                                                   float* __restrict__ cnt) {
    int t = threadIdx.x;
    int cg = t & 31, rg = t >> 5;
    int c0 = cg * 4;
    float4 sc = *(const float4*)(scale + c0);
    float4 sh = *(const float4*)(shift + c0);
    int per = (N_NODES + gridDim.x - 1) / gridDim.x;
    int rstart = blockIdx.x * per;
    int rend = min(rstart + per, N_NODES);
    float4 acc = make_float4(0, 0, 0, 0);
    float runc = 0.0f;
    int cur = -1;
    for (int rowi = rstart + rg; rowi < rend; rowi += 8) {
        int g = batch[rowi];
        if (g != cur) {
            if (cur >= 0) {
                unsafeAtomicAdd(&pooled[(size_t)cur * H + c0 + 0], acc.x);
                unsafeAtomicAdd(&pooled[(size_t)cur * H + c0 + 1], acc.y);
                unsafeAtomicAdd(&pooled[(size_t)cur * H + c0 + 2], acc.z);
                unsafeAtomicAdd(&pooled[(size_t)cur * H + c0 + 3], acc.w);
                if (cg == 0) unsafeAtomicAdd(&cnt[cur], runc);
            }
            cur = g; acc = make_float4(0, 0, 0, 0); runc = 0.0f;
        }
        float4 v = *(const float4*)(hh + (size_t)rowi * H + c0);
        acc.x += v.x * sc.x + sh.x;
        acc.y += v.y * sc.y + sh.y;
        acc.z += v.z * sc.z + sh.z;
        acc.w += v.w * sc.w + sh.w;
        runc += 1.0f;
    }
    if (cur >= 0) {
        unsafeAtomicAdd(&pooled[(size_t)cur * H + c0 + 0], acc.x);
        unsafeAtomicAdd(&pooled[(size_t)cur * H + c0 + 1], acc.y);
        unsafeAtomicAdd(&pooled[(size_t)cur * H + c0 + 2], acc.z);
        unsafeAtomicAdd(&pooled[(size_t)cur * H + c0 + 3], acc.w);
        if (cg == 0) unsafeAtomicAdd(&cnt[cur], runc);
    }
}

__global__ __launch_bounds__(128) void final_gemm(const float* __restrict__ pooled,
                                                  const float* __restrict__ cnt,
                                                  const float* __restrict__ Wout,
                                                  const float* __restrict__ bout,
                                                  float* __restrict__ out) {
    __shared__ float sh[H];
    int g = blockIdx.x;
    int o = threadIdx.x;
    float c = fmaxf(cnt[g], 1.0f);
    sh[o] = pooled[(size_t)g * H + o] / c;
    __syncthreads();
    float acc = bout[o];
#pragma unroll 8
    for (int k = 0; k < H; k++) acc += sh[k] * Wout[(size_t)k * OUT_F + o];
    out[(size_t)g * OUT_F + o] = acc;
}

extern "C" void kernel_launch(void* const* d_in, const int* in_sizes, int n_in,
                              void* d_out, int out_size, void* d_ws, size_t ws_size,
                              hipStream_t stream) {
    const int*   x     = (const int*)d_in[0];
    const int*   ei    = (const int*)d_in[1];
    const float* ea    = (const float*)d_in[2];
    const int*   batch = (const int*)d_in[3];
    const float* nemb  = (const float*)d_in[4];
    const float* W     = (const float*)d_in[5];
    const float* b     = (const float*)d_in[6];
    const float* We    = (const float*)d_in[7];
    const float* be    = (const float*)d_in[8];
    const float* root  = (const float*)d_in[9];
    const float* gamma = (const float*)d_in[10];
    const float* beta  = (const float*)d_in[11];
    const float* Wout  = (const float*)d_in[12];
    const float* bout  = (const float*)d_in[13];
    float* out = (float*)d_out;

    const int* erow = ei;
    const int* ecol = ei + N_EDGES;

    float* ws = (float*)d_ws;
    size_t NH = (size_t)N_NODES * H;
    float* ea8    = ws;                              // E*8 floats
    int*   rows   = (int*)(ea8 + (size_t)N_EDGES * 8);   // E ints
    float* hpre   = (float*)(rows + N_EDGES);
    float* xl     = hpre + NH;
    int*   rowptr = (int*)(xl + NH);                 // N+1 (+pad)
    float* dis    = (float*)(rowptr + N_NODES + 4);
    float* invdeg = dis + N_NODES;
    float* colsum   = invdeg + N_NODES;              // 128
    float* colsumsq = colsum + H;                    // 128
    float* scale    = colsumsq + H;                  // 128
    float* shift    = scale + H;                     // 128
    float* pooled   = shift + H;                     // G*H
    float* cnt      = pooled + (size_t)G_GRAPHS * H; // G

    // preprocessing temps alias into hpre region (hpre first written in layer 0 agg)
    int* degcnt = (int*)hpre;
    int* hist   = degcnt + N_NODES;
    int* cursor = hist + N_NODES;

    hipMemsetAsync(degcnt, 0, 2 * N_NODES * sizeof(int), stream);
    hipLaunchKernelGGL(count_kernel, dim3(N_EDGES / 256), dim3(256), 0, stream,
                       erow, ecol, degcnt, hist);
    hipLaunchKernelGGL(finish_deg, dim3((N_NODES + 255) / 256), dim3(256), 0, stream,
                       degcnt, dis, invdeg);
    hipLaunchKernelGGL(scan_hist, dim3(1), dim3(1024), 0, stream, hist, rowptr, cursor);
    hipLaunchKernelGGL(scatter_kernel, dim3(N_EDGES / 256), dim3(256), 0, stream,
                       erow, ecol, ea, dis, cursor, ea8, rows);

    for (int l = 0; l < L_LAYERS; l++) {
        hipLaunchKernelGGL(gemm_xl, dim3((N_NODES + 127) / 128), dim3(256), 0, stream,
                           hpre, x, nemb, scale, shift,
                           W + (size_t)l * H * H, b + (size_t)l * H, xl,
                           (l == 0) ? 0 : 1);
        hipMemsetAsync(colsum, 0, 2 * H * sizeof(float), stream);
        hipLaunchKernelGGL(agg_kernel, dim3(2048), dim3(256), 0, stream,
                           rowptr, ea8, rows, xl, invdeg,
                           root + (size_t)l * H, We + (size_t)l * 7 * H, be + (size_t)l * H,
                           hpre, colsum, colsumsq);
        hipLaunchKernelGGL(bn_finalize, dim3(1), dim3(H), 0, stream,
                           colsum, colsumsq, gamma + (size_t)l * H, beta + (size_t)l * H,
                           scale, shift);
    }

    hipMemsetAsync(pooled, 0, ((size_t)G_GRAPHS * H + G_GRAPHS) * sizeof(float), stream);
    hipLaunchKernelGGL(pool_kernel, dim3(256), dim3(256), 0, stream,
                       hpre, batch, scale, shift, pooled, cnt);
    hipLaunchKernelGGL(final_gemm, dim3(G_GRAPHS), dim3(OUT_F), 0, stream,
                       pooled, cnt, Wout, bout, out);
}

// Round 4
// 1819.345 us; speedup vs baseline: 4.0598x; 1.1246x over previous
//
#include <hip/hip_runtime.h>
#include <cstdint>
#include <cstddef>

#define N_NODES 100000
#define N_EDGES 1600000
#define H 128
#define L_LAYERS 5
#define G_GRAPHS 128
#define OUT_F 128
#define BN_EPS 1e-5f
#define SCAN_BLOCKS 98   // ceil(100000/1024)

__device__ __forceinline__ float frelu(float x) { return fmaxf(x, 0.0f); }

// ================= preprocessing =================

__global__ void count_kernel(const int* __restrict__ erow, const int* __restrict__ ecol,
                             int* __restrict__ degcnt, int* __restrict__ hist) {
    int e = blockIdx.x * 256 + threadIdx.x;  // E divisible by 256
    atomicAdd(&degcnt[erow[e]], 1);
    atomicAdd(&hist[ecol[e]], 1);
}

__global__ void finish_deg(const int* __restrict__ degcnt, float* __restrict__ dis,
                           float* __restrict__ invdeg) {
    int i = blockIdx.x * 256 + threadIdx.x;
    if (i < N_NODES) {
        float d = (float)degcnt[i] + 1.0f;
        dis[i] = rsqrtf(d);
        invdeg[i] = 1.0f / d;
    }
}

// ---- two-level scan: part (per-block exclusive scan) ----
__global__ __launch_bounds__(1024) void scan_part(const int* __restrict__ hist,
                                                  int* __restrict__ rowptr,
                                                  int* __restrict__ blocksum) {
    int t = threadIdx.x;
    int i = blockIdx.x * 1024 + t;
    int orig = (i < N_NODES) ? hist[i] : 0;
    int v = orig;
    // wave-64 inclusive scan
#pragma unroll
    for (int off = 1; off < 64; off <<= 1) {
        int u = __shfl_up(v, off);
        if ((t & 63) >= off) v += u;
    }
    __shared__ int wsum[16];
    int wid = t >> 6;
    if ((t & 63) == 63) wsum[wid] = v;
    __syncthreads();
    int woff = 0;
#pragma unroll
    for (int w = 0; w < 16; w++)
        if (w < wid) woff += wsum[w];
    int incl = v + woff;
    if (i < N_NODES) rowptr[i] = incl - orig;  // exclusive, block-local
    if (t == 1023) blocksum[blockIdx.x] = incl;
}

// ---- scan of the 98 block sums (1 block, 128 threads) ----
__global__ __launch_bounds__(128) void scan_block(const int* __restrict__ blocksum,
                                                  int* __restrict__ blockoff,
                                                  int* __restrict__ rowptr) {
    int t = threadIdx.x;
    int orig = (t < SCAN_BLOCKS) ? blocksum[t] : 0;
    int v = orig;
#pragma unroll
    for (int off = 1; off < 64; off <<= 1) {
        int u = __shfl_up(v, off);
        if ((t & 63) >= off) v += u;
    }
    __shared__ int w0;
    if (t == 63) w0 = v;
    __syncthreads();
    if (t >= 64) v += w0;
    if (t < SCAN_BLOCKS) blockoff[t] = v - orig;  // exclusive
    if (t == 0) rowptr[N_NODES] = N_EDGES;
}

// ---- add block offsets, emit cursor copy ----
__global__ __launch_bounds__(1024) void scan_add(int* __restrict__ rowptr,
                                                 const int* __restrict__ blockoff,
                                                 int* __restrict__ cursor) {
    int i = blockIdx.x * 1024 + threadIdx.x;
    if (i < N_NODES) {
        int v = rowptr[i] + blockoff[blockIdx.x];
        rowptr[i] = v;
        cursor[i] = v;
    }
}

// permute edge payloads into col-sorted order:
//   ea8[pos*8] = {ea[0..6], norm}   rows[pos] = row
__global__ void scatter_kernel(const int* __restrict__ erow, const int* __restrict__ ecol,
                               const float* __restrict__ ea, const float* __restrict__ dis,
                               int* __restrict__ cursor,
                               float* __restrict__ ea8, int* __restrict__ rows) {
    int e = blockIdx.x * 256 + threadIdx.x;
    int c = ecol[e];
    int r = erow[e];
    float nrm = dis[r] * dis[c];
    int pos = atomicAdd(&cursor[c], 1);
    const float* p = ea + (size_t)e * 7;
    float a0 = p[0], a1 = p[1], a2 = p[2], a3 = p[3], a4 = p[4], a5 = p[5], a6 = p[6];
    float* dst = ea8 + (size_t)pos * 8;
    *(float4*)dst = make_float4(a0, a1, a2, a3);
    *(float4*)(dst + 4) = make_float4(a4, a5, a6, nrm);
    rows[pos] = r;
}

// ================= xl = act(h) @ W + b =================
// mode 0: h = node_emb[x[row]]; mode 1: h = relu(hpre*scale+shift),
// scale/shift recomputed in-block from prev layer's colsum/colsumsq.
__global__ __launch_bounds__(256) void gemm_xl(const float* __restrict__ hsrc,
                                               const int* __restrict__ xidx,
                                               const float* __restrict__ nemb,
                                               const float* __restrict__ colsum_p,
                                               const float* __restrict__ colsumsq_p,
                                               const float* __restrict__ gamma_p,
                                               const float* __restrict__ beta_p,
                                               const float* __restrict__ Wl,
                                               const float* __restrict__ bl,
                                               float* __restrict__ xlo, int mode) {
    constexpr int KC = 32;
    constexpr int HPITCH = 33;
    constexpr int WPITCH = 132;
    __shared__ float sH[128 * HPITCH];
    __shared__ float sW[KC * WPITCH];
    __shared__ float sScale[H], sShift[H];
    int t = threadIdx.x;
    if (mode == 1) {
        if (t < H) {
            float mean = colsum_p[t] * (1.0f / N_NODES);
            float var = colsumsq_p[t] * (1.0f / N_NODES) - mean * mean;
            float s = gamma_p[t] * rsqrtf(var + BN_EPS);
            sScale[t] = s;
            sShift[t] = beta_p[t] - mean * s;
        }
        __syncthreads();
    }
    int tx = t & 15, ty = t >> 4;
    int r0 = blockIdx.x * 128;
    int c0 = tx * 8;
    int rbase = ty * 8;
    float acc[8][8];
#pragma unroll
    for (int i = 0; i < 8; i++)
#pragma unroll
        for (int j = 0; j < 8; j++) acc[i][j] = 0.0f;

    for (int kc = 0; kc < H; kc += KC) {
        for (int idx = t; idx < 1024; idx += 256) {
            int rowi = idx >> 3;
            int kg = idx & 7;
            int gr = r0 + rowi; if (gr > N_NODES - 1) gr = N_NODES - 1;
            float4 v;
            if (mode == 0) {
                int xv = xidx[gr];
                v = *(const float4*)(nemb + (size_t)xv * H + kc + kg * 4);
            } else {
                v = *(const float4*)(hsrc + (size_t)gr * H + kc + kg * 4);
                float4 sc = *(const float4*)&sScale[kc + kg * 4];
                float4 sh = *(const float4*)&sShift[kc + kg * 4];
                v.x = frelu(v.x * sc.x + sh.x);
                v.y = frelu(v.y * sc.y + sh.y);
                v.z = frelu(v.z * sc.z + sh.z);
                v.w = frelu(v.w * sc.w + sh.w);
            }
            float* d = &sH[rowi * HPITCH + kg * 4];
            d[0] = v.x; d[1] = v.y; d[2] = v.z; d[3] = v.w;
        }
        for (int idx = t; idx < 1024; idx += 256) {
            int k = idx >> 5;
            int cg = idx & 31;
            *(float4*)&sW[k * WPITCH + cg * 4] =
                *(const float4*)(Wl + (size_t)(kc + k) * H + cg * 4);
        }
        __syncthreads();
#pragma unroll 4
        for (int k = 0; k < KC; k++) {
            float4 w0 = *(const float4*)&sW[k * WPITCH + c0];
            float4 w1 = *(const float4*)&sW[k * WPITCH + c0 + 4];
#pragma unroll
            for (int i = 0; i < 8; i++) {
                float hv = sH[(rbase + i) * HPITCH + k];
                acc[i][0] += hv * w0.x; acc[i][1] += hv * w0.y;
                acc[i][2] += hv * w0.z; acc[i][3] += hv * w0.w;
                acc[i][4] += hv * w1.x; acc[i][5] += hv * w1.y;
                acc[i][6] += hv * w1.z; acc[i][7] += hv * w1.w;
            }
        }
        __syncthreads();
    }
    float4 b0 = *(const float4*)(bl + c0);
    float4 b1 = *(const float4*)(bl + c0 + 4);
#pragma unroll
    for (int i = 0; i < 8; i++) {
        int row = r0 + rbase + i;
        if (row < N_NODES) {
            float4 o0 = make_float4(acc[i][0] + b0.x, acc[i][1] + b0.y,
                                    acc[i][2] + b0.z, acc[i][3] + b0.w);
            float4 o1 = make_float4(acc[i][4] + b1.x, acc[i][5] + b1.y,
                                    acc[i][6] + b1.z, acc[i][7] + b1.w);
            *(float4*)(xlo + (size_t)row * H + c0) = o0;
            *(float4*)(xlo + (size_t)row * H + c0 + 4) = o1;
        }
    }
}

// ================= gather aggregation + BN stats =================
__global__ __launch_bounds__(256) void agg_kernel(
    const int* __restrict__ rowptr, const float* __restrict__ ea8,
    const int* __restrict__ rows, const float* __restrict__ xl,
    const float* __restrict__ invdeg, const float* __restrict__ rootl,
    const float* __restrict__ Wel, const float* __restrict__ bel,
    float* __restrict__ hpre, float* __restrict__ colsum,
    float* __restrict__ colsumsq) {
    int t = threadIdx.x;
    int lane = t & 63, wv = t >> 6;
    int c0 = lane * 2;
    float w00 = Wel[0 * H + c0], w01 = Wel[0 * H + c0 + 1];
    float w10 = Wel[1 * H + c0], w11 = Wel[1 * H + c0 + 1];
    float w20 = Wel[2 * H + c0], w21 = Wel[2 * H + c0 + 1];
    float w30 = Wel[3 * H + c0], w31 = Wel[3 * H + c0 + 1];
    float w40 = Wel[4 * H + c0], w41 = Wel[4 * H + c0 + 1];
    float w50 = Wel[5 * H + c0], w51 = Wel[5 * H + c0 + 1];
    float w60 = Wel[6 * H + c0], w61 = Wel[6 * H + c0 + 1];
    float be0 = bel[c0], be1 = bel[c0 + 1];
    float rt0 = rootl[c0], rt1 = rootl[c0 + 1];
    float s0 = 0, s1 = 0, q0 = 0, q1 = 0;

#define EDGE_BODY(JJ)                                                        \
    {                                                                        \
        int r_ = rows[(JJ)];                                                 \
        const float* ep_ = ea8 + (size_t)(JJ) * 8;                           \
        float4 v0_ = *(const float4*)ep_;                                    \
        float4 v1_ = *(const float4*)(ep_ + 4);                              \
        float2 xg_ = *(const float2*)(xl + (size_t)r_ * H + c0);             \
        float m0_ = be0, m1_ = be1;                                          \
        m0_ = fmaf(v0_.x, w00, m0_); m1_ = fmaf(v0_.x, w01, m1_);            \
        m0_ = fmaf(v0_.y, w10, m0_); m1_ = fmaf(v0_.y, w11, m1_);            \
        m0_ = fmaf(v0_.z, w20, m0_); m1_ = fmaf(v0_.z, w21, m1_);            \
        m0_ = fmaf(v0_.w, w30, m0_); m1_ = fmaf(v0_.w, w31, m1_);            \
        m0_ = fmaf(v1_.x, w40, m0_); m1_ = fmaf(v1_.x, w41, m1_);            \
        m0_ = fmaf(v1_.y, w50, m0_); m1_ = fmaf(v1_.y, w51, m1_);            \
        m0_ = fmaf(v1_.z, w60, m0_); m1_ = fmaf(v1_.z, w61, m1_);            \
        a0 = fmaf(frelu(xg_.x + m0_), v1_.w, a0);                            \
        a1 = fmaf(frelu(xg_.y + m1_), v1_.w, a1);                            \
    }

    for (int n = blockIdx.x * 4 + wv; n < N_NODES; n += gridDim.x * 4) {
        int jb = rowptr[n], je = rowptr[n + 1];
        float a0 = 0, a1 = 0;
        int j = jb;
        for (; j + 4 <= je; j += 4) {
            EDGE_BODY(j);
            EDGE_BODY(j + 1);
            EDGE_BODY(j + 2);
            EDGE_BODY(j + 3);
        }
        for (; j < je; j++) EDGE_BODY(j);
        float2 xn = *(const float2*)(xl + (size_t)n * H + c0);
        float id = invdeg[n];
        float p0 = a0 + frelu(xn.x + rt0) * id;
        float p1 = a1 + frelu(xn.y + rt1) * id;
        *(float2*)(hpre + (size_t)n * H + c0) = make_float2(p0, p1);
        s0 += p0; s1 += p1;
        q0 = fmaf(p0, p0, q0); q1 = fmaf(p1, p1, q1);
    }
#undef EDGE_BODY

    __shared__ float red[4][H];
    red[wv][c0] = s0; red[wv][c0 + 1] = s1;
    __syncthreads();
    if (wv == 0) {
        float t0 = red[0][c0] + red[1][c0] + red[2][c0] + red[3][c0];
        float t1 = red[0][c0 + 1] + red[1][c0 + 1] + red[2][c0 + 1] + red[3][c0 + 1];
        unsafeAtomicAdd(&colsum[c0], t0);
        unsafeAtomicAdd(&colsum[c0 + 1], t1);
    }
    __syncthreads();
    red[wv][c0] = q0; red[wv][c0 + 1] = q1;
    __syncthreads();
    if (wv == 0) {
        float t0 = red[0][c0] + red[1][c0] + red[2][c0] + red[3][c0];
        float t1 = red[0][c0 + 1] + red[1][c0 + 1] + red[2][c0 + 1] + red[3][c0 + 1];
        unsafeAtomicAdd(&colsumsq[c0], t0);
        unsafeAtomicAdd(&colsumsq[c0 + 1], t1);
    }
}

// ================= pool (applies final BN in-kernel) =================
__global__ __launch_bounds__(256) void pool_kernel(const float* __restrict__ hh,
                                                   const int* __restrict__ batch,
                                                   const float* __restrict__ colsum_p,
                                                   const float* __restrict__ colsumsq_p,
                                                   const float* __restrict__ gamma_p,
                                                   const float* __restrict__ beta_p,
                                                   float* __restrict__ pooled,
                                                   float* __restrict__ cnt) {
    __shared__ float sScale[H], sShift[H];
    int t = threadIdx.x;
    if (t < H) {
        float mean = colsum_p[t] * (1.0f / N_NODES);
        float var = colsumsq_p[t] * (1.0f / N_NODES) - mean * mean;
        float s = gamma_p[t] * rsqrtf(var + BN_EPS);
        sScale[t] = s;
        sShift[t] = beta_p[t] - mean * s;
    }
    __syncthreads();
    int cg = t & 31, rg = t >> 5;
    int c0 = cg * 4;
    float4 sc = *(const float4*)&sScale[c0];
    float4 sh = *(const float4*)&sShift[c0];
    int per = (N_NODES + gridDim.x - 1) / gridDim.x;
    int rstart = blockIdx.x * per;
    int rend = min(rstart + per, N_NODES);
    float4 acc = make_float4(0, 0, 0, 0);
    float runc = 0.0f;
    int cur = -1;
    for (int rowi = rstart + rg; rowi < rend; rowi += 8) {
        int g = batch[rowi];
        if (g != cur) {
            if (cur >= 0) {
                unsafeAtomicAdd(&pooled[(size_t)cur * H + c0 + 0], acc.x);
                unsafeAtomicAdd(&pooled[(size_t)cur * H + c0 + 1], acc.y);
                unsafeAtomicAdd(&pooled[(size_t)cur * H + c0 + 2], acc.z);
                unsafeAtomicAdd(&pooled[(size_t)cur * H + c0 + 3], acc.w);
                if (cg == 0) unsafeAtomicAdd(&cnt[cur], runc);
            }
            cur = g; acc = make_float4(0, 0, 0, 0); runc = 0.0f;
        }
        float4 v = *(const float4*)(hh + (size_t)rowi * H + c0);
        acc.x += v.x * sc.x + sh.x;
        acc.y += v.y * sc.y + sh.y;
        acc.z += v.z * sc.z + sh.z;
        acc.w += v.w * sc.w + sh.w;
        runc += 1.0f;
    }
    if (cur >= 0) {
        unsafeAtomicAdd(&pooled[(size_t)cur * H + c0 + 0], acc.x);
        unsafeAtomicAdd(&pooled[(size_t)cur * H + c0 + 1], acc.y);
        unsafeAtomicAdd(&pooled[(size_t)cur * H + c0 + 2], acc.z);
        unsafeAtomicAdd(&pooled[(size_t)cur * H + c0 + 3], acc.w);
        if (cg == 0) unsafeAtomicAdd(&cnt[cur], runc);
    }
}

__global__ __launch_bounds__(128) void final_gemm(const float* __restrict__ pooled,
                                                  const float* __restrict__ cnt,
                                                  const float* __restrict__ Wout,
                                                  const float* __restrict__ bout,
                                                  float* __restrict__ out) {
    __shared__ float sh[H];
    int g = blockIdx.x;
    int o = threadIdx.x;
    float c = fmaxf(cnt[g], 1.0f);
    sh[o] = pooled[(size_t)g * H + o] / c;
    __syncthreads();
    float acc = bout[o];
#pragma unroll 8
    for (int k = 0; k < H; k++) acc += sh[k] * Wout[(size_t)k * OUT_F + o];
    out[(size_t)g * OUT_F + o] = acc;
}

extern "C" void kernel_launch(void* const* d_in, const int* in_sizes, int n_in,
                              void* d_out, int out_size, void* d_ws, size_t ws_size,
                              hipStream_t stream) {
    const int*   x     = (const int*)d_in[0];
    const int*   ei    = (const int*)d_in[1];
    const float* ea    = (const float*)d_in[2];
    const int*   batch = (const int*)d_in[3];
    const float* nemb  = (const float*)d_in[4];
    const float* W     = (const float*)d_in[5];
    const float* b     = (const float*)d_in[6];
    const float* We    = (const float*)d_in[7];
    const float* be    = (const float*)d_in[8];
    const float* root  = (const float*)d_in[9];
    const float* gamma = (const float*)d_in[10];
    const float* beta  = (const float*)d_in[11];
    const float* Wout  = (const float*)d_in[12];
    const float* bout  = (const float*)d_in[13];
    float* out = (float*)d_out;

    const int* erow = ei;
    const int* ecol = ei + N_EDGES;

    float* ws = (float*)d_ws;
    size_t NH = (size_t)N_NODES * H;
    float* ea8    = ws;                              // E*8 floats
    int*   rows   = (int*)(ea8 + (size_t)N_EDGES * 8);   // E ints
    float* hpre   = (float*)(rows + N_EDGES);
    float* xl     = hpre + NH;
    int*   rowptr = (int*)(xl + NH);                 // N+1 (+pad)
    float* dis    = (float*)(rowptr + N_NODES + 4);
    float* invdeg = dis + N_NODES;
    float* colsumAll = invdeg + N_NODES;             // L*2*H floats (per-layer sum|sumsq)
    float* pooled   = colsumAll + (size_t)L_LAYERS * 2 * H;  // G*H
    float* cnt      = pooled + (size_t)G_GRAPHS * H; // G
    int*   blocksum = (int*)(cnt + G_GRAPHS);        // 128
    int*   blockoff = blocksum + 128;                // 128

    // preprocessing temps alias into hpre region (hpre first written in layer 0 agg)
    int* degcnt = (int*)hpre;
    int* hist   = degcnt + N_NODES;
    int* cursor = hist + N_NODES;

    hipMemsetAsync(degcnt, 0, 2 * N_NODES * sizeof(int), stream);
    hipMemsetAsync(colsumAll, 0, (size_t)L_LAYERS * 2 * H * sizeof(float), stream);
    hipLaunchKernelGGL(count_kernel, dim3(N_EDGES / 256), dim3(256), 0, stream,
                       erow, ecol, degcnt, hist);
    hipLaunchKernelGGL(finish_deg, dim3((N_NODES + 255) / 256), dim3(256), 0, stream,
                       degcnt, dis, invdeg);
    hipLaunchKernelGGL(scan_part, dim3(SCAN_BLOCKS), dim3(1024), 0, stream,
                       hist, rowptr, blocksum);
    hipLaunchKernelGGL(scan_block, dim3(1), dim3(128), 0, stream,
                       blocksum, blockoff, rowptr);
    hipLaunchKernelGGL(scan_add, dim3(SCAN_BLOCKS), dim3(1024), 0, stream,
                       rowptr, blockoff, cursor);
    hipLaunchKernelGGL(scatter_kernel, dim3(N_EDGES / 256), dim3(256), 0, stream,
                       erow, ecol, ea, dis, cursor, ea8, rows);

    for (int l = 0; l < L_LAYERS; l++) {
        const float* cs_prev = colsumAll + (size_t)(l - 1) * 2 * H;  // unused when l==0
        hipLaunchKernelGGL(gemm_xl, dim3((N_NODES + 127) / 128), dim3(256), 0, stream,
                           hpre, x, nemb,
                           (l == 0) ? colsumAll : cs_prev,
                           (l == 0) ? colsumAll : cs_prev + H,
                           gamma + (size_t)(l ? l - 1 : 0) * H,
                           beta + (size_t)(l ? l - 1 : 0) * H,
                           W + (size_t)l * H * H, b + (size_t)l * H, xl,
                           (l == 0) ? 0 : 1);
        float* cs = colsumAll + (size_t)l * 2 * H;
        hipLaunchKernelGGL(agg_kernel, dim3(2048), dim3(256), 0, stream,
                           rowptr, ea8, rows, xl, invdeg,
                           root + (size_t)l * H, We + (size_t)l * 7 * H, be + (size_t)l * H,
                           hpre, cs, cs + H);
    }

    hipMemsetAsync(pooled, 0, ((size_t)G_GRAPHS * H + G_GRAPHS) * sizeof(float), stream);
    {
        const float* cs4 = colsumAll + (size_t)(L_LAYERS - 1) * 2 * H;
        hipLaunchKernelGGL(pool_kernel, dim3(256), dim3(256), 0, stream,
                           hpre, batch, cs4, cs4 + H,
                           gamma + (size_t)(L_LAYERS - 1) * H,
                           beta + (size_t)(L_LAYERS - 1) * H, pooled, cnt);
    }
    hipLaunchKernelGGL(final_gemm, dim3(G_GRAPHS), dim3(OUT_F), 0, stream,
                       pooled, cnt, Wout, bout, out);
}

// Round 5
// 1668.119 us; speedup vs baseline: 4.4279x; 1.0907x over previous
//
#include <hip/hip_runtime.h>
#include <hip/hip_fp16.h>
#include <cstdint>
#include <cstddef>

#define N_NODES 100000
#define N_EDGES 1600000
#define H 128
#define L_LAYERS 5
#define G_GRAPHS 128
#define OUT_F 128
#define BN_EPS 1e-5f
#define SCAN_BLOCKS 98   // ceil(100000/1024)

__device__ __forceinline__ float frelu(float x) { return fmaxf(x, 0.0f); }

// ================= preprocessing =================

__global__ void count_kernel(const int* __restrict__ erow, const int* __restrict__ ecol,
                             int* __restrict__ degcnt, int* __restrict__ hist) {
    int e = blockIdx.x * 256 + threadIdx.x;  // E divisible by 256
    atomicAdd(&degcnt[erow[e]], 1);
    atomicAdd(&hist[ecol[e]], 1);
}

__global__ void finish_deg(const int* __restrict__ degcnt, float* __restrict__ dis,
                           float* __restrict__ invdeg) {
    int i = blockIdx.x * 256 + threadIdx.x;
    if (i < N_NODES) {
        float d = (float)degcnt[i] + 1.0f;
        dis[i] = rsqrtf(d);
        invdeg[i] = 1.0f / d;
    }
}

// ---- two-level scan ----
__global__ __launch_bounds__(1024) void scan_part(const int* __restrict__ hist,
                                                  int* __restrict__ rowptr,
                                                  int* __restrict__ blocksum) {
    int t = threadIdx.x;
    int i = blockIdx.x * 1024 + t;
    int orig = (i < N_NODES) ? hist[i] : 0;
    int v = orig;
#pragma unroll
    for (int off = 1; off < 64; off <<= 1) {
        int u = __shfl_up(v, off);
        if ((t & 63) >= off) v += u;
    }
    __shared__ int wsum[16];
    int wid = t >> 6;
    if ((t & 63) == 63) wsum[wid] = v;
    __syncthreads();
    int woff = 0;
#pragma unroll
    for (int w = 0; w < 16; w++)
        if (w < wid) woff += wsum[w];
    int incl = v + woff;
    if (i < N_NODES) rowptr[i] = incl - orig;
    if (t == 1023) blocksum[blockIdx.x] = incl;
}

__global__ __launch_bounds__(128) void scan_block(const int* __restrict__ blocksum,
                                                  int* __restrict__ blockoff,
                                                  int* __restrict__ rowptr) {
    int t = threadIdx.x;
    int orig = (t < SCAN_BLOCKS) ? blocksum[t] : 0;
    int v = orig;
#pragma unroll
    for (int off = 1; off < 64; off <<= 1) {
        int u = __shfl_up(v, off);
        if ((t & 63) >= off) v += u;
    }
    __shared__ int w0;
    if (t == 63) w0 = v;
    __syncthreads();
    if (t >= 64) v += w0;
    if (t < SCAN_BLOCKS) blockoff[t] = v - orig;
    if (t == 0) rowptr[N_NODES] = N_EDGES;
}

__global__ __launch_bounds__(1024) void scan_add(int* __restrict__ rowptr,
                                                 const int* __restrict__ blockoff,
                                                 int* __restrict__ cursor) {
    int i = blockIdx.x * 1024 + threadIdx.x;
    if (i < N_NODES) {
        int v = rowptr[i] + blockoff[blockIdx.x];
        rowptr[i] = v;
        cursor[i] = v;
    }
}

// permute edge payloads into col-sorted order
__global__ void scatter_kernel(const int* __restrict__ erow, const int* __restrict__ ecol,
                               const float* __restrict__ ea, const float* __restrict__ dis,
                               int* __restrict__ cursor,
                               float* __restrict__ ea8, int* __restrict__ rows) {
    int e = blockIdx.x * 256 + threadIdx.x;
    int c = ecol[e];
    int r = erow[e];
    float nrm = dis[r] * dis[c];
    int pos = atomicAdd(&cursor[c], 1);
    const float* p = ea + (size_t)e * 7;
    float a0 = p[0], a1 = p[1], a2 = p[2], a3 = p[3], a4 = p[4], a5 = p[5], a6 = p[6];
    float* dst = ea8 + (size_t)pos * 8;
    *(float4*)dst = make_float4(a0, a1, a2, a3);
    *(float4*)(dst + 4) = make_float4(a4, a5, a6, nrm);
    rows[pos] = r;
}

// ================= xl = act(h) @ W + b  (fp16 output) =================
__global__ __launch_bounds__(256) void gemm_xl(const float* __restrict__ hsrc,
                                               const int* __restrict__ xidx,
                                               const float* __restrict__ nemb,
                                               const float* __restrict__ colsum_p,
                                               const float* __restrict__ colsumsq_p,
                                               const float* __restrict__ gamma_p,
                                               const float* __restrict__ beta_p,
                                               const float* __restrict__ Wl,
                                               const float* __restrict__ bl,
                                               __half* __restrict__ xlo, int mode) {
    constexpr int KC = 32;
    constexpr int HPITCH = 33;
    constexpr int WPITCH = 132;
    __shared__ float sH[128 * HPITCH];
    __shared__ float sW[KC * WPITCH];
    __shared__ float sScale[H], sShift[H];
    int t = threadIdx.x;
    if (mode == 1) {
        if (t < H) {
            float mean = colsum_p[t] * (1.0f / N_NODES);
            float var = colsumsq_p[t] * (1.0f / N_NODES) - mean * mean;
            float s = gamma_p[t] * rsqrtf(var + BN_EPS);
            sScale[t] = s;
            sShift[t] = beta_p[t] - mean * s;
        }
        __syncthreads();
    }
    int tx = t & 15, ty = t >> 4;
    int r0 = blockIdx.x * 128;
    int c0 = tx * 8;
    int rbase = ty * 8;
    float acc[8][8];
#pragma unroll
    for (int i = 0; i < 8; i++)
#pragma unroll
        for (int j = 0; j < 8; j++) acc[i][j] = 0.0f;

    for (int kc = 0; kc < H; kc += KC) {
        for (int idx = t; idx < 1024; idx += 256) {
            int rowi = idx >> 3;
            int kg = idx & 7;
            int gr = r0 + rowi; if (gr > N_NODES - 1) gr = N_NODES - 1;
            float4 v;
            if (mode == 0) {
                int xv = xidx[gr];
                v = *(const float4*)(nemb + (size_t)xv * H + kc + kg * 4);
            } else {
                v = *(const float4*)(hsrc + (size_t)gr * H + kc + kg * 4);
                float4 sc = *(const float4*)&sScale[kc + kg * 4];
                float4 sh = *(const float4*)&sShift[kc + kg * 4];
                v.x = frelu(v.x * sc.x + sh.x);
                v.y = frelu(v.y * sc.y + sh.y);
                v.z = frelu(v.z * sc.z + sh.z);
                v.w = frelu(v.w * sc.w + sh.w);
            }
            float* d = &sH[rowi * HPITCH + kg * 4];
            d[0] = v.x; d[1] = v.y; d[2] = v.z; d[3] = v.w;
        }
        for (int idx = t; idx < 1024; idx += 256) {
            int k = idx >> 5;
            int cg = idx & 31;
            *(float4*)&sW[k * WPITCH + cg * 4] =
                *(const float4*)(Wl + (size_t)(kc + k) * H + cg * 4);
        }
        __syncthreads();
#pragma unroll 4
        for (int k = 0; k < KC; k++) {
            float4 w0 = *(const float4*)&sW[k * WPITCH + c0];
            float4 w1 = *(const float4*)&sW[k * WPITCH + c0 + 4];
#pragma unroll
            for (int i = 0; i < 8; i++) {
                float hv = sH[(rbase + i) * HPITCH + k];
                acc[i][0] += hv * w0.x; acc[i][1] += hv * w0.y;
                acc[i][2] += hv * w0.z; acc[i][3] += hv * w0.w;
                acc[i][4] += hv * w1.x; acc[i][5] += hv * w1.y;
                acc[i][6] += hv * w1.z; acc[i][7] += hv * w1.w;
            }
        }
        __syncthreads();
    }
    float4 b0 = *(const float4*)(bl + c0);
    float4 b1 = *(const float4*)(bl + c0 + 4);
#pragma unroll
    for (int i = 0; i < 8; i++) {
        int row = r0 + rbase + i;
        if (row < N_NODES) {
            union { float4 f4; __half2 h2v[4]; } u;
            u.h2v[0] = __float22half2_rn(make_float2(acc[i][0] + b0.x, acc[i][1] + b0.y));
            u.h2v[1] = __float22half2_rn(make_float2(acc[i][2] + b0.z, acc[i][3] + b0.w));
            u.h2v[2] = __float22half2_rn(make_float2(acc[i][4] + b1.x, acc[i][5] + b1.y));
            u.h2v[3] = __float22half2_rn(make_float2(acc[i][6] + b1.z, acc[i][7] + b1.w));
            *(float4*)(xlo + (size_t)row * H + c0) = u.f4;
        }
    }
}

// ================= gather aggregation + BN stats =================
// wave per node; lane owns cols {2*lane, 2*lane+1}; xl gathered as half2.
__global__ __launch_bounds__(256) void agg_kernel(
    const int* __restrict__ rowptr, const float* __restrict__ ea8,
    const int* __restrict__ rows, const __half2* __restrict__ xh2,
    const float* __restrict__ invdeg, const float* __restrict__ rootl,
    const float* __restrict__ Wel, const float* __restrict__ bel,
    float* __restrict__ hpre, float* __restrict__ colsum,
    float* __restrict__ colsumsq) {
    int t = threadIdx.x;
    int lane = t & 63, wv = t >> 6;
    int c0 = lane * 2;
    float w00 = Wel[0 * H + c0], w01 = Wel[0 * H + c0 + 1];
    float w10 = Wel[1 * H + c0], w11 = Wel[1 * H + c0 + 1];
    float w20 = Wel[2 * H + c0], w21 = Wel[2 * H + c0 + 1];
    float w30 = Wel[3 * H + c0], w31 = Wel[3 * H + c0 + 1];
    float w40 = Wel[4 * H + c0], w41 = Wel[4 * H + c0 + 1];
    float w50 = Wel[5 * H + c0], w51 = Wel[5 * H + c0 + 1];
    float w60 = Wel[6 * H + c0], w61 = Wel[6 * H + c0 + 1];
    float be0 = bel[c0], be1 = bel[c0 + 1];
    float rt0 = rootl[c0], rt1 = rootl[c0 + 1];
    float s0 = 0, s1 = 0, q0 = 0, q1 = 0;

#define MLP_BODY(V0, V1, XG)                                                 \
    {                                                                        \
        float2 xg_ = __half22float2(XG);                                     \
        float m0_ = be0, m1_ = be1;                                          \
        m0_ = fmaf((V0).x, w00, m0_); m1_ = fmaf((V0).x, w01, m1_);          \
        m0_ = fmaf((V0).y, w10, m0_); m1_ = fmaf((V0).y, w11, m1_);          \
        m0_ = fmaf((V0).z, w20, m0_); m1_ = fmaf((V0).z, w21, m1_);          \
        m0_ = fmaf((V0).w, w30, m0_); m1_ = fmaf((V0).w, w31, m1_);          \
        m0_ = fmaf((V1).x, w40, m0_); m1_ = fmaf((V1).x, w41, m1_);          \
        m0_ = fmaf((V1).y, w50, m0_); m1_ = fmaf((V1).y, w51, m1_);          \
        m0_ = fmaf((V1).z, w60, m0_); m1_ = fmaf((V1).z, w61, m1_);          \
        a0 = fmaf(frelu(xg_.x + m0_), (V1).w, a0);                           \
        a1 = fmaf(frelu(xg_.y + m1_), (V1).w, a1);                           \
    }

    for (int n = blockIdx.x * 4 + wv; n < N_NODES; n += gridDim.x * 4) {
        int jb = rowptr[n], je = rowptr[n + 1];
        float a0 = 0, a1 = 0;
        int j = jb;
        for (; j + 4 <= je; j += 4) {
            // batch the 4 index loads first, then the 4 gathers (MLP overlaps)
            int r0_ = rows[j], r1_ = rows[j + 1], r2_ = rows[j + 2], r3_ = rows[j + 3];
            const float* e0_ = ea8 + (size_t)j * 8;
            float4 p0a = *(const float4*)e0_,       p0b = *(const float4*)(e0_ + 4);
            float4 p1a = *(const float4*)(e0_ + 8),  p1b = *(const float4*)(e0_ + 12);
            float4 p2a = *(const float4*)(e0_ + 16), p2b = *(const float4*)(e0_ + 20);
            float4 p3a = *(const float4*)(e0_ + 24), p3b = *(const float4*)(e0_ + 28);
            __half2 g0 = xh2[(size_t)r0_ * 64 + lane];
            __half2 g1 = xh2[(size_t)r1_ * 64 + lane];
            __half2 g2 = xh2[(size_t)r2_ * 64 + lane];
            __half2 g3 = xh2[(size_t)r3_ * 64 + lane];
            MLP_BODY(p0a, p0b, g0);
            MLP_BODY(p1a, p1b, g1);
            MLP_BODY(p2a, p2b, g2);
            MLP_BODY(p3a, p3b, g3);
        }
        for (; j < je; j++) {
            int r_ = rows[j];
            const float* ep_ = ea8 + (size_t)j * 8;
            float4 va = *(const float4*)ep_, vb = *(const float4*)(ep_ + 4);
            __half2 g_ = xh2[(size_t)r_ * 64 + lane];
            MLP_BODY(va, vb, g_);
        }
        float2 xn = __half22float2(xh2[(size_t)n * 64 + lane]);
        float id = invdeg[n];
        float p0 = a0 + frelu(xn.x + rt0) * id;
        float p1 = a1 + frelu(xn.y + rt1) * id;
        *(float2*)(hpre + (size_t)n * H + c0) = make_float2(p0, p1);
        s0 += p0; s1 += p1;
        q0 = fmaf(p0, p0, q0); q1 = fmaf(p1, p1, q1);
    }
#undef MLP_BODY

    __shared__ float red[4][H];
    red[wv][c0] = s0; red[wv][c0 + 1] = s1;
    __syncthreads();
    if (wv == 0) {
        float t0 = red[0][c0] + red[1][c0] + red[2][c0] + red[3][c0];
        float t1 = red[0][c0 + 1] + red[1][c0 + 1] + red[2][c0 + 1] + red[3][c0 + 1];
        unsafeAtomicAdd(&colsum[c0], t0);
        unsafeAtomicAdd(&colsum[c0 + 1], t1);
    }
    __syncthreads();
    red[wv][c0] = q0; red[wv][c0 + 1] = q1;
    __syncthreads();
    if (wv == 0) {
        float t0 = red[0][c0] + red[1][c0] + red[2][c0] + red[3][c0];
        float t1 = red[0][c0 + 1] + red[1][c0 + 1] + red[2][c0 + 1] + red[3][c0 + 1];
        unsafeAtomicAdd(&colsumsq[c0], t0);
        unsafeAtomicAdd(&colsumsq[c0 + 1], t1);
    }
}

// ================= pool (applies final BN in-kernel) =================
__global__ __launch_bounds__(256) void pool_kernel(const float* __restrict__ hh,
                                                   const int* __restrict__ batch,
                                                   const float* __restrict__ colsum_p,
                                                   const float* __restrict__ colsumsq_p,
                                                   const float* __restrict__ gamma_p,
                                                   const float* __restrict__ beta_p,
                                                   float* __restrict__ pooled,
                                                   float* __restrict__ cnt) {
    __shared__ float sScale[H], sShift[H];
    int t = threadIdx.x;
    if (t < H) {
        float mean = colsum_p[t] * (1.0f / N_NODES);
        float var = colsumsq_p[t] * (1.0f / N_NODES) - mean * mean;
        float s = gamma_p[t] * rsqrtf(var + BN_EPS);
        sScale[t] = s;
        sShift[t] = beta_p[t] - mean * s;
    }
    __syncthreads();
    int cg = t & 31, rg = t >> 5;
    int c0 = cg * 4;
    float4 sc = *(const float4*)&sScale[c0];
    float4 sh = *(const float4*)&sShift[c0];
    int per = (N_NODES + gridDim.x - 1) / gridDim.x;
    int rstart = blockIdx.x * per;
    int rend = min(rstart + per, N_NODES);
    float4 acc = make_float4(0, 0, 0, 0);
    float runc = 0.0f;
    int cur = -1;
    for (int rowi = rstart + rg; rowi < rend; rowi += 8) {
        int g = batch[rowi];
        if (g != cur) {
            if (cur >= 0) {
                unsafeAtomicAdd(&pooled[(size_t)cur * H + c0 + 0], acc.x);
                unsafeAtomicAdd(&pooled[(size_t)cur * H + c0 + 1], acc.y);
                unsafeAtomicAdd(&pooled[(size_t)cur * H + c0 + 2], acc.z);
                unsafeAtomicAdd(&pooled[(size_t)cur * H + c0 + 3], acc.w);
                if (cg == 0) unsafeAtomicAdd(&cnt[cur], runc);
            }
            cur = g; acc = make_float4(0, 0, 0, 0); runc = 0.0f;
        }
        float4 v = *(const float4*)(hh + (size_t)rowi * H + c0);
        acc.x += v.x * sc.x + sh.x;
        acc.y += v.y * sc.y + sh.y;
        acc.z += v.z * sc.z + sh.z;
        acc.w += v.w * sc.w + sh.w;
        runc += 1.0f;
    }
    if (cur >= 0) {
        unsafeAtomicAdd(&pooled[(size_t)cur * H + c0 + 0], acc.x);
        unsafeAtomicAdd(&pooled[(size_t)cur * H + c0 + 1], acc.y);
        unsafeAtomicAdd(&pooled[(size_t)cur * H + c0 + 2], acc.z);
        unsafeAtomicAdd(&pooled[(size_t)cur * H + c0 + 3], acc.w);
        if (cg == 0) unsafeAtomicAdd(&cnt[cur], runc);
    }
}

__global__ __launch_bounds__(128) void final_gemm(const float* __restrict__ pooled,
                                                  const float* __restrict__ cnt,
                                                  const float* __restrict__ Wout,
                                                  const float* __restrict__ bout,
                                                  float* __restrict__ out) {
    __shared__ float sh[H];
    int g = blockIdx.x;
    int o = threadIdx.x;
    float c = fmaxf(cnt[g], 1.0f);
    sh[o] = pooled[(size_t)g * H + o] / c;
    __syncthreads();
    float acc = bout[o];
#pragma unroll 8
    for (int k = 0; k < H; k++) acc += sh[k] * Wout[(size_t)k * OUT_F + o];
    out[(size_t)g * OUT_F + o] = acc;
}

extern "C" void kernel_launch(void* const* d_in, const int* in_sizes, int n_in,
                              void* d_out, int out_size, void* d_ws, size_t ws_size,
                              hipStream_t stream) {
    const int*   x     = (const int*)d_in[0];
    const int*   ei    = (const int*)d_in[1];
    const float* ea    = (const float*)d_in[2];
    const int*   batch = (const int*)d_in[3];
    const float* nemb  = (const float*)d_in[4];
    const float* W     = (const float*)d_in[5];
    const float* b     = (const float*)d_in[6];
    const float* We    = (const float*)d_in[7];
    const float* be    = (const float*)d_in[8];
    const float* root  = (const float*)d_in[9];
    const float* gamma = (const float*)d_in[10];
    const float* beta  = (const float*)d_in[11];
    const float* Wout  = (const float*)d_in[12];
    const float* bout  = (const float*)d_in[13];
    float* out = (float*)d_out;

    const int* erow = ei;
    const int* ecol = ei + N_EDGES;

    float* ws = (float*)d_ws;
    size_t NH = (size_t)N_NODES * H;
    float* ea8    = ws;                              // E*8 floats
    int*   rows   = (int*)(ea8 + (size_t)N_EDGES * 8);   // E ints
    float* hpre   = (float*)(rows + N_EDGES);
    float* xlslot = hpre + NH;                       // NH floats reserved; used as half
    __half* xlh   = (__half*)xlslot;
    int*   rowptr = (int*)(xlslot + NH);             // N+1 (+pad)
    float* dis    = (float*)(rowptr + N_NODES + 4);
    float* invdeg = dis + N_NODES;
    float* colsumAll = invdeg + N_NODES;             // L*2*H floats
    float* pooled   = colsumAll + (size_t)L_LAYERS * 2 * H;
    float* cnt      = pooled + (size_t)G_GRAPHS * H;
    int*   blocksum = (int*)(cnt + G_GRAPHS);        // 128
    int*   blockoff = blocksum + 128;                // 128

    // preprocessing temps alias into hpre region
    int* degcnt = (int*)hpre;
    int* hist   = degcnt + N_NODES;
    int* cursor = hist + N_NODES;

    hipMemsetAsync(degcnt, 0, 2 * N_NODES * sizeof(int), stream);
    hipMemsetAsync(colsumAll, 0, (size_t)L_LAYERS * 2 * H * sizeof(float), stream);
    hipLaunchKernelGGL(count_kernel, dim3(N_EDGES / 256), dim3(256), 0, stream,
                       erow, ecol, degcnt, hist);
    hipLaunchKernelGGL(finish_deg, dim3((N_NODES + 255) / 256), dim3(256), 0, stream,
                       degcnt, dis, invdeg);
    hipLaunchKernelGGL(scan_part, dim3(SCAN_BLOCKS), dim3(1024), 0, stream,
                       hist, rowptr, blocksum);
    hipLaunchKernelGGL(scan_block, dim3(1), dim3(128), 0, stream,
                       blocksum, blockoff, rowptr);
    hipLaunchKernelGGL(scan_add, dim3(SCAN_BLOCKS), dim3(1024), 0, stream,
                       rowptr, blockoff, cursor);
    hipLaunchKernelGGL(scatter_kernel, dim3(N_EDGES / 256), dim3(256), 0, stream,
                       erow, ecol, ea, dis, cursor, ea8, rows);

    for (int l = 0; l < L_LAYERS; l++) {
        const float* cs_prev = colsumAll + (size_t)(l - 1) * 2 * H;  // unused when l==0
        hipLaunchKernelGGL(gemm_xl, dim3((N_NODES + 127) / 128), dim3(256), 0, stream,
                           hpre, x, nemb,
                           (l == 0) ? colsumAll : cs_prev,
                           (l == 0) ? colsumAll : cs_prev + H,
                           gamma + (size_t)(l ? l - 1 : 0) * H,
                           beta + (size_t)(l ? l - 1 : 0) * H,
                           W + (size_t)l * H * H, b + (size_t)l * H, xlh,
                           (l == 0) ? 0 : 1);
        float* cs = colsumAll + (size_t)l * 2 * H;
        hipLaunchKernelGGL(agg_kernel, dim3(2048), dim3(256), 0, stream,
                           rowptr, ea8, rows, (const __half2*)xlh, invdeg,
                           root + (size_t)l * H, We + (size_t)l * 7 * H, be + (size_t)l * H,
                           hpre, cs, cs + H);
    }

    hipMemsetAsync(pooled, 0, ((size_t)G_GRAPHS * H + G_GRAPHS) * sizeof(float), stream);
    {
        const float* cs4 = colsumAll + (size_t)(L_LAYERS - 1) * 2 * H;
        hipLaunchKernelGGL(pool_kernel, dim3(256), dim3(256), 0, stream,
                           hpre, batch, cs4, cs4 + H,
                           gamma + (size_t)(L_LAYERS - 1) * H,
                           beta + (size_t)(L_LAYERS - 1) * H, pooled, cnt);
    }
    hipLaunchKernelGGL(final_gemm, dim3(G_GRAPHS), dim3(OUT_F), 0, stream,
                       pooled, cnt, Wout, bout, out);
}

// Round 6
// 1372.008 us; speedup vs baseline: 5.3835x; 1.2158x over previous
//
#include <hip/hip_runtime.h>
#include <hip/hip_fp16.h>
#include <cstdint>
#include <cstddef>

#define N_NODES 100000
#define N_EDGES 1600000
#define H 128
#define L_LAYERS 5
#define G_GRAPHS 128
#define OUT_F 128
#define BN_EPS 1e-5f
#define SCAN_BLOCKS 98   // ceil(100000/1024)

typedef _Float16 half8_t __attribute__((ext_vector_type(8)));
typedef float floatx4 __attribute__((ext_vector_type(4)));

__device__ __forceinline__ float frelu(float x) { return fmaxf(x, 0.0f); }

// ================= preprocessing =================

__global__ void count_kernel(const int* __restrict__ erow, const int* __restrict__ ecol,
                             int* __restrict__ degcnt, int* __restrict__ hist) {
    int e = blockIdx.x * 256 + threadIdx.x;  // E divisible by 256
    atomicAdd(&degcnt[erow[e]], 1);
    atomicAdd(&hist[ecol[e]], 1);
}

__global__ void finish_deg(const int* __restrict__ degcnt, float* __restrict__ dis,
                           float* __restrict__ invdeg) {
    int i = blockIdx.x * 256 + threadIdx.x;
    if (i < N_NODES) {
        float d = (float)degcnt[i] + 1.0f;
        dis[i] = rsqrtf(d);
        invdeg[i] = 1.0f / d;
    }
}

// ---- two-level scan ----
__global__ __launch_bounds__(1024) void scan_part(const int* __restrict__ hist,
                                                  int* __restrict__ rowptr,
                                                  int* __restrict__ blocksum) {
    int t = threadIdx.x;
    int i = blockIdx.x * 1024 + t;
    int orig = (i < N_NODES) ? hist[i] : 0;
    int v = orig;
#pragma unroll
    for (int off = 1; off < 64; off <<= 1) {
        int u = __shfl_up(v, off);
        if ((t & 63) >= off) v += u;
    }
    __shared__ int wsum[16];
    int wid = t >> 6;
    if ((t & 63) == 63) wsum[wid] = v;
    __syncthreads();
    int woff = 0;
#pragma unroll
    for (int w = 0; w < 16; w++)
        if (w < wid) woff += wsum[w];
    int incl = v + woff;
    if (i < N_NODES) rowptr[i] = incl - orig;
    if (t == 1023) blocksum[blockIdx.x] = incl;
}

__global__ __launch_bounds__(128) void scan_block(const int* __restrict__ blocksum,
                                                  int* __restrict__ blockoff,
                                                  int* __restrict__ rowptr) {
    int t = threadIdx.x;
    int orig = (t < SCAN_BLOCKS) ? blocksum[t] : 0;
    int v = orig;
#pragma unroll
    for (int off = 1; off < 64; off <<= 1) {
        int u = __shfl_up(v, off);
        if ((t & 63) >= off) v += u;
    }
    __shared__ int w0;
    if (t == 63) w0 = v;
    __syncthreads();
    if (t >= 64) v += w0;
    if (t < SCAN_BLOCKS) blockoff[t] = v - orig;
    if (t == 0) rowptr[N_NODES] = N_EDGES;
}

__global__ __launch_bounds__(1024) void scan_add(int* __restrict__ rowptr,
                                                 const int* __restrict__ blockoff,
                                                 int* __restrict__ cursor) {
    int i = blockIdx.x * 1024 + threadIdx.x;
    if (i < N_NODES) {
        int v = rowptr[i] + blockoff[blockIdx.x];
        rowptr[i] = v;
        cursor[i] = v;
    }
}

// permute edge payloads into col-sorted order
__global__ void scatter_kernel(const int* __restrict__ erow, const int* __restrict__ ecol,
                               const float* __restrict__ ea, const float* __restrict__ dis,
                               int* __restrict__ cursor,
                               float* __restrict__ ea8, int* __restrict__ rows) {
    int e = blockIdx.x * 256 + threadIdx.x;
    int c = ecol[e];
    int r = erow[e];
    float nrm = dis[r] * dis[c];
    int pos = atomicAdd(&cursor[c], 1);
    const float* p = ea + (size_t)e * 7;
    float a0 = p[0], a1 = p[1], a2 = p[2], a3 = p[3], a4 = p[4], a5 = p[5], a6 = p[6];
    float* dst = ea8 + (size_t)pos * 8;
    *(float4*)dst = make_float4(a0, a1, a2, a3);
    *(float4*)(dst + 4) = make_float4(a4, a5, a6, nrm);
    rows[pos] = r;
}

// ================= xl = act(h) @ W + b  via MFMA f16 =================
// block = 256 thr (4 waves), tile = 128 rows; each wave: 32 rows x 128 cols.
// A = BN+relu(hpre fp16) or node_emb[x[row]] (mode 0), converted to f16 frags.
// B = W staged in LDS pre-swizzled into mfma B-fragment layout (f16).
// mfma_f32_16x16x32_f16: A lane l: row=l&15, k=(l>>4)*8+i ; B: col=l&15, same k.
// C: col=lane&15, row=(lane>>4)*4+reg.
__global__ __launch_bounds__(256) void gemm_xl(const __half* __restrict__ hsrc,
                                               const int* __restrict__ xidx,
                                               const float* __restrict__ nemb,
                                               const float* __restrict__ colsum_p,
                                               const float* __restrict__ colsumsq_p,
                                               const float* __restrict__ gamma_p,
                                               const float* __restrict__ beta_p,
                                               const float* __restrict__ Wl,
                                               const float* __restrict__ bl,
                                               __half* __restrict__ xlo, int mode) {
    __shared__ half8_t sB[2048];          // [ct][ks][lane] fragments, 32 KB
    __shared__ float sScale[H], sShift[H];
    int t = threadIdx.x;
    if (mode == 1 && t < H) {
        float mean = colsum_p[t] * (1.0f / N_NODES);
        float var = colsumsq_p[t] * (1.0f / N_NODES) - mean * mean;
        float s = gamma_p[t] * rsqrtf(var + BN_EPS);
        sScale[t] = s;
        sShift[t] = beta_p[t] - mean * s;
    }
    // stage W as B-fragments
    for (int idx = t; idx < 2048; idx += 256) {
        int ct = idx >> 8;
        int ks = (idx >> 6) & 3;
        int ln = idx & 63;
        int kbase = ks * 32 + (ln >> 4) * 8;
        int c = ct * 16 + (ln & 15);
        half8_t v;
#pragma unroll
        for (int i = 0; i < 8; i++)
            v[i] = (_Float16)Wl[(size_t)(kbase + i) * H + c];
        sB[idx] = v;
    }
    __syncthreads();

    int w = t >> 6, lane = t & 63;
    int lq = lane >> 4, lr = lane & 15;
    int rbase = blockIdx.x * 128 + w * 32;

    floatx4 acc[2][8];
#pragma unroll
    for (int rt = 0; rt < 2; rt++)
#pragma unroll
        for (int ct = 0; ct < 8; ct++) acc[rt][ct] = (floatx4)0.0f;

    float bias[8];
#pragma unroll
    for (int ct = 0; ct < 8; ct++) bias[ct] = bl[ct * 16 + lr];

    int arow[2], xv[2];
#pragma unroll
    for (int rt = 0; rt < 2; rt++) {
        int row = rbase + rt * 16 + lr;
        if (row > N_NODES - 1) row = N_NODES - 1;
        arow[rt] = row;
        if (mode == 0) xv[rt] = xidx[row];
    }

    for (int ks = 0; ks < 4; ks++) {
        int k0 = ks * 32 + lq * 8;
        half8_t a[2];
#pragma unroll
        for (int rt = 0; rt < 2; rt++) {
            float f[8];
            if (mode == 0) {
                const float* p = nemb + (size_t)xv[rt] * H + k0;
                float4 u0 = *(const float4*)p;
                float4 u1 = *(const float4*)(p + 4);
                f[0] = u0.x; f[1] = u0.y; f[2] = u0.z; f[3] = u0.w;
                f[4] = u1.x; f[5] = u1.y; f[6] = u1.z; f[7] = u1.w;
            } else {
                union { float4 f4; __half2 h2[4]; } u;
                u.f4 = *(const float4*)(hsrc + (size_t)arow[rt] * H + k0);
#pragma unroll
                for (int i = 0; i < 4; i++) {
                    float2 d = __half22float2(u.h2[i]);
                    f[2 * i] = d.x; f[2 * i + 1] = d.y;
                }
#pragma unroll
                for (int i = 0; i < 8; i++)
                    f[i] = frelu(f[i] * sScale[k0 + i] + sShift[k0 + i]);
            }
            half8_t av;
#pragma unroll
            for (int i = 0; i < 8; i++) av[i] = (_Float16)f[i];
            a[rt] = av;
        }
#pragma unroll
        for (int ct = 0; ct < 8; ct++) {
            half8_t bf = sB[(ct * 4 + ks) * 64 + lane];
            acc[0][ct] = __builtin_amdgcn_mfma_f32_16x16x32_f16(a[0], bf, acc[0][ct], 0, 0, 0);
            acc[1][ct] = __builtin_amdgcn_mfma_f32_16x16x32_f16(a[1], bf, acc[1][ct], 0, 0, 0);
        }
    }

#pragma unroll
    for (int rt = 0; rt < 2; rt++)
#pragma unroll
        for (int ct = 0; ct < 8; ct++)
#pragma unroll
            for (int r = 0; r < 4; r++) {
                int row = rbase + rt * 16 + lq * 4 + r;
                if (row < N_NODES)
                    xlo[(size_t)row * H + ct * 16 + lr] =
                        __float2half(acc[rt][ct][r] + bias[ct]);
            }
}

// ================= gather aggregation + BN stats =================
// wave per node; lane owns cols {2*lane, 2*lane+1}; xl gathered as half2;
// hpre written as half2. n/jb/je scalarized via readfirstlane so the
// wave-uniform rows/payload loads can use the scalar pipe.
__global__ __launch_bounds__(256) void agg_kernel(
    const int* __restrict__ rowptr, const float* __restrict__ ea8,
    const int* __restrict__ rows, const __half2* __restrict__ xh2,
    const float* __restrict__ invdeg, const float* __restrict__ rootl,
    const float* __restrict__ Wel, const float* __restrict__ bel,
    __half2* __restrict__ hpreh, float* __restrict__ colsum,
    float* __restrict__ colsumsq) {
    int t = threadIdx.x;
    int lane = t & 63, wv = t >> 6;
    int c0 = lane * 2;
    float w00 = Wel[0 * H + c0], w01 = Wel[0 * H + c0 + 1];
    float w10 = Wel[1 * H + c0], w11 = Wel[1 * H + c0 + 1];
    float w20 = Wel[2 * H + c0], w21 = Wel[2 * H + c0 + 1];
    float w30 = Wel[3 * H + c0], w31 = Wel[3 * H + c0 + 1];
    float w40 = Wel[4 * H + c0], w41 = Wel[4 * H + c0 + 1];
    float w50 = Wel[5 * H + c0], w51 = Wel[5 * H + c0 + 1];
    float w60 = Wel[6 * H + c0], w61 = Wel[6 * H + c0 + 1];
    float be0 = bel[c0], be1 = bel[c0 + 1];
    float rt0 = rootl[c0], rt1 = rootl[c0 + 1];
    float s0 = 0, s1 = 0, q0 = 0, q1 = 0;

#define MLP_BODY(V0, V1, XG)                                                 \
    {                                                                        \
        float2 xg_ = __half22float2(XG);                                     \
        float m0_ = be0, m1_ = be1;                                          \
        m0_ = fmaf((V0).x, w00, m0_); m1_ = fmaf((V0).x, w01, m1_);          \
        m0_ = fmaf((V0).y, w10, m0_); m1_ = fmaf((V0).y, w11, m1_);          \
        m0_ = fmaf((V0).z, w20, m0_); m1_ = fmaf((V0).z, w21, m1_);          \
        m0_ = fmaf((V0).w, w30, m0_); m1_ = fmaf((V0).w, w31, m1_);          \
        m0_ = fmaf((V1).x, w40, m0_); m1_ = fmaf((V1).x, w41, m1_);          \
        m0_ = fmaf((V1).y, w50, m0_); m1_ = fmaf((V1).y, w51, m1_);          \
        m0_ = fmaf((V1).z, w60, m0_); m1_ = fmaf((V1).z, w61, m1_);          \
        a0 = fmaf(frelu(xg_.x + m0_), (V1).w, a0);                           \
        a1 = fmaf(frelu(xg_.y + m1_), (V1).w, a1);                           \
    }

    for (int n_ = blockIdx.x * 4 + wv; n_ < N_NODES; n_ += gridDim.x * 4) {
        int n = __builtin_amdgcn_readfirstlane(n_);
        int jb = __builtin_amdgcn_readfirstlane(rowptr[n]);
        int je = __builtin_amdgcn_readfirstlane(rowptr[n + 1]);
        float a0 = 0, a1 = 0;
        int j = jb;
        for (; j + 4 <= je; j += 4) {
            int r0_ = rows[j], r1_ = rows[j + 1], r2_ = rows[j + 2], r3_ = rows[j + 3];
            const float* e0_ = ea8 + (size_t)j * 8;
            float4 p0a = *(const float4*)e0_,        p0b = *(const float4*)(e0_ + 4);
            float4 p1a = *(const float4*)(e0_ + 8),  p1b = *(const float4*)(e0_ + 12);
            float4 p2a = *(const float4*)(e0_ + 16), p2b = *(const float4*)(e0_ + 20);
            float4 p3a = *(const float4*)(e0_ + 24), p3b = *(const float4*)(e0_ + 28);
            __half2 g0 = xh2[(size_t)r0_ * 64 + lane];
            __half2 g1 = xh2[(size_t)r1_ * 64 + lane];
            __half2 g2 = xh2[(size_t)r2_ * 64 + lane];
            __half2 g3 = xh2[(size_t)r3_ * 64 + lane];
            MLP_BODY(p0a, p0b, g0);
            MLP_BODY(p1a, p1b, g1);
            MLP_BODY(p2a, p2b, g2);
            MLP_BODY(p3a, p3b, g3);
        }
        for (; j < je; j++) {
            int r_ = rows[j];
            const float* ep_ = ea8 + (size_t)j * 8;
            float4 va = *(const float4*)ep_, vb = *(const float4*)(ep_ + 4);
            __half2 g_ = xh2[(size_t)r_ * 64 + lane];
            MLP_BODY(va, vb, g_);
        }
        float2 xn = __half22float2(xh2[(size_t)n * 64 + lane]);
        float id = invdeg[n];
        float p0 = a0 + frelu(xn.x + rt0) * id;
        float p1 = a1 + frelu(xn.y + rt1) * id;
        hpreh[(size_t)n * 64 + lane] = __float22half2_rn(make_float2(p0, p1));
        s0 += p0; s1 += p1;
        q0 = fmaf(p0, p0, q0); q1 = fmaf(p1, p1, q1);
    }
#undef MLP_BODY

    __shared__ float red[4][H];
    red[wv][c0] = s0; red[wv][c0 + 1] = s1;
    __syncthreads();
    if (wv == 0) {
        float t0 = red[0][c0] + red[1][c0] + red[2][c0] + red[3][c0];
        float t1 = red[0][c0 + 1] + red[1][c0 + 1] + red[2][c0 + 1] + red[3][c0 + 1];
        unsafeAtomicAdd(&colsum[c0], t0);
        unsafeAtomicAdd(&colsum[c0 + 1], t1);
    }
    __syncthreads();
    red[wv][c0] = q0; red[wv][c0 + 1] = q1;
    __syncthreads();
    if (wv == 0) {
        float t0 = red[0][c0] + red[1][c0] + red[2][c0] + red[3][c0];
        float t1 = red[0][c0 + 1] + red[1][c0 + 1] + red[2][c0 + 1] + red[3][c0 + 1];
        unsafeAtomicAdd(&colsumsq[c0], t0);
        unsafeAtomicAdd(&colsumsq[c0 + 1], t1);
    }
}

// ================= pool (applies final BN in-kernel, fp16 input) =================
__global__ __launch_bounds__(256) void pool_kernel(const __half2* __restrict__ hh,
                                                   const int* __restrict__ batch,
                                                   const float* __restrict__ colsum_p,
                                                   const float* __restrict__ colsumsq_p,
                                                   const float* __restrict__ gamma_p,
                                                   const float* __restrict__ beta_p,
                                                   float* __restrict__ pooled,
                                                   float* __restrict__ cnt) {
    __shared__ float sScale[H], sShift[H];
    int t = threadIdx.x;
    if (t < H) {
        float mean = colsum_p[t] * (1.0f / N_NODES);
        float var = colsumsq_p[t] * (1.0f / N_NODES) - mean * mean;
        float s = gamma_p[t] * rsqrtf(var + BN_EPS);
        sScale[t] = s;
        sShift[t] = beta_p[t] - mean * s;
    }
    __syncthreads();
    int cg = t & 63, rg = t >> 6;
    int c0 = cg * 2;
    float sc0 = sScale[c0], sc1 = sScale[c0 + 1];
    float sh0 = sShift[c0], sh1 = sShift[c0 + 1];
    int per = (N_NODES + gridDim.x - 1) / gridDim.x;
    int rstart = blockIdx.x * per;
    int rend = min(rstart + per, N_NODES);
    float a0 = 0, a1 = 0, runc = 0.0f;
    int cur = -1;
    for (int rowi = rstart + rg; rowi < rend; rowi += 4) {
        int g = batch[rowi];
        if (g != cur) {
            if (cur >= 0) {
                unsafeAtomicAdd(&pooled[(size_t)cur * H + c0 + 0], a0);
                unsafeAtomicAdd(&pooled[(size_t)cur * H + c0 + 1], a1);
                if (cg == 0) unsafeAtomicAdd(&cnt[cur], runc);
            }
            cur = g; a0 = 0; a1 = 0; runc = 0.0f;
        }
        float2 v = __half22float2(hh[(size_t)rowi * 64 + cg]);
        a0 += v.x * sc0 + sh0;
        a1 += v.y * sc1 + sh1;
        runc += 1.0f;
    }
    if (cur >= 0) {
        unsafeAtomicAdd(&pooled[(size_t)cur * H + c0 + 0], a0);
        unsafeAtomicAdd(&pooled[(size_t)cur * H + c0 + 1], a1);
        if (cg == 0) unsafeAtomicAdd(&cnt[cur], runc);
    }
}

__global__ __launch_bounds__(128) void final_gemm(const float* __restrict__ pooled,
                                                  const float* __restrict__ cnt,
                                                  const float* __restrict__ Wout,
                                                  const float* __restrict__ bout,
                                                  float* __restrict__ out) {
    __shared__ float sh[H];
    int g = blockIdx.x;
    int o = threadIdx.x;
    float c = fmaxf(cnt[g], 1.0f);
    sh[o] = pooled[(size_t)g * H + o] / c;
    __syncthreads();
    float acc = bout[o];
#pragma unroll 8
    for (int k = 0; k < H; k++) acc += sh[k] * Wout[(size_t)k * OUT_F + o];
    out[(size_t)g * OUT_F + o] = acc;
}

extern "C" void kernel_launch(void* const* d_in, const int* in_sizes, int n_in,
                              void* d_out, int out_size, void* d_ws, size_t ws_size,
                              hipStream_t stream) {
    const int*   x     = (const int*)d_in[0];
    const int*   ei    = (const int*)d_in[1];
    const float* ea    = (const float*)d_in[2];
    const int*   batch = (const int*)d_in[3];
    const float* nemb  = (const float*)d_in[4];
    const float* W     = (const float*)d_in[5];
    const float* b     = (const float*)d_in[6];
    const float* We    = (const float*)d_in[7];
    const float* be    = (const float*)d_in[8];
    const float* root  = (const float*)d_in[9];
    const float* gamma = (const float*)d_in[10];
    const float* beta  = (const float*)d_in[11];
    const float* Wout  = (const float*)d_in[12];
    const float* bout  = (const float*)d_in[13];
    float* out = (float*)d_out;

    const int* erow = ei;
    const int* ecol = ei + N_EDGES;

    float* ws = (float*)d_ws;
    size_t NH = (size_t)N_NODES * H;
    float* ea8    = ws;                                  // E*8 floats
    int*   rows   = (int*)(ea8 + (size_t)N_EDGES * 8);   // E ints
    float* hslot  = (float*)(rows + N_EDGES);            // NH/2 floats (fp16 hpre)
    __half* hpreh = (__half*)hslot;
    float* xslot  = hslot + NH / 2;                      // NH/2 floats (fp16 xl)
    __half* xlh   = (__half*)xslot;
    int*   rowptr = (int*)(xslot + NH / 2);              // N+1 (+pad)
    float* dis    = (float*)(rowptr + N_NODES + 4);
    float* invdeg = dis + N_NODES;
    float* colsumAll = invdeg + N_NODES;                 // L*2*H floats
    float* pooled   = colsumAll + (size_t)L_LAYERS * 2 * H;
    float* cnt      = pooled + (size_t)G_GRAPHS * H;
    int*   blocksum = (int*)(cnt + G_GRAPHS);            // 128
    int*   blockoff = blocksum + 128;                    // 128

    // preprocessing temps alias into hpre region (hpre first written in layer 0 agg)
    int* degcnt = (int*)hslot;
    int* hist   = degcnt + N_NODES;
    int* cursor = hist + N_NODES;

    hipMemsetAsync(degcnt, 0, 2 * N_NODES * sizeof(int), stream);
    hipMemsetAsync(colsumAll, 0, (size_t)L_LAYERS * 2 * H * sizeof(float), stream);
    hipLaunchKernelGGL(count_kernel, dim3(N_EDGES / 256), dim3(256), 0, stream,
                       erow, ecol, degcnt, hist);
    hipLaunchKernelGGL(finish_deg, dim3((N_NODES + 255) / 256), dim3(256), 0, stream,
                       degcnt, dis, invdeg);
    hipLaunchKernelGGL(scan_part, dim3(SCAN_BLOCKS), dim3(1024), 0, stream,
                       hist, rowptr, blocksum);
    hipLaunchKernelGGL(scan_block, dim3(1), dim3(128), 0, stream,
                       blocksum, blockoff, rowptr);
    hipLaunchKernelGGL(scan_add, dim3(SCAN_BLOCKS), dim3(1024), 0, stream,
                       rowptr, blockoff, cursor);
    hipLaunchKernelGGL(scatter_kernel, dim3(N_EDGES / 256), dim3(256), 0, stream,
                       erow, ecol, ea, dis, cursor, ea8, rows);

    for (int l = 0; l < L_LAYERS; l++) {
        const float* cs_prev = colsumAll + (size_t)(l - 1) * 2 * H;  // unused when l==0
        hipLaunchKernelGGL(gemm_xl, dim3((N_NODES + 127) / 128), dim3(256), 0, stream,
                           hpreh, x, nemb,
                           (l == 0) ? colsumAll : cs_prev,
                           (l == 0) ? colsumAll : cs_prev + H,
                           gamma + (size_t)(l ? l - 1 : 0) * H,
                           beta + (size_t)(l ? l - 1 : 0) * H,
                           W + (size_t)l * H * H, b + (size_t)l * H, xlh,
                           (l == 0) ? 0 : 1);
        float* cs = colsumAll + (size_t)l * 2 * H;
        hipLaunchKernelGGL(agg_kernel, dim3(2048), dim3(256), 0, stream,
                           rowptr, ea8, rows, (const __half2*)xlh, invdeg,
                           root + (size_t)l * H, We + (size_t)l * 7 * H, be + (size_t)l * H,
                           (__half2*)hpreh, cs, cs + H);
    }

    hipMemsetAsync(pooled, 0, ((size_t)G_GRAPHS * H + G_GRAPHS) * sizeof(float), stream);
    {
        const float* cs4 = colsumAll + (size_t)(L_LAYERS - 1) * 2 * H;
        hipLaunchKernelGGL(pool_kernel, dim3(256), dim3(256), 0, stream,
                           (const __half2*)hpreh, batch, cs4, cs4 + H,
                           gamma + (size_t)(L_LAYERS - 1) * H,
                           beta + (size_t)(L_LAYERS - 1) * H, pooled, cnt);
    }
    hipLaunchKernelGGL(final_gemm, dim3(G_GRAPHS), dim3(OUT_F), 0, stream,
                       pooled, cnt, Wout, bout, out);
}

// Round 7
// 1364.716 us; speedup vs baseline: 5.4122x; 1.0053x over previous
//
#include <hip/hip_runtime.h>
#include <hip/hip_fp16.h>
#include <cstdint>
#include <cstddef>

#define N_NODES 100000
#define N_EDGES 1600000
#define H 128
#define L_LAYERS 5
#define G_GRAPHS 128
#define OUT_F 128
#define BN_EPS 1e-5f
#define SCAN_BLOCKS 98   // ceil(100000/1024)

typedef _Float16 half8_t __attribute__((ext_vector_type(8)));
typedef float floatx4 __attribute__((ext_vector_type(4)));

__device__ __forceinline__ float frelu(float x) { return fmaxf(x, 0.0f); }

// ================= preprocessing =================

__global__ void count_kernel(const int* __restrict__ erow, const int* __restrict__ ecol,
                             int* __restrict__ degcnt, int* __restrict__ hist) {
    int e = blockIdx.x * 256 + threadIdx.x;  // E divisible by 256
    atomicAdd(&degcnt[erow[e]], 1);
    atomicAdd(&hist[ecol[e]], 1);
}

__global__ void finish_deg(const int* __restrict__ degcnt, float* __restrict__ dis,
                           float* __restrict__ invdeg) {
    int i = blockIdx.x * 256 + threadIdx.x;
    if (i < N_NODES) {
        float d = (float)degcnt[i] + 1.0f;
        dis[i] = rsqrtf(d);
        invdeg[i] = 1.0f / d;
    }
}

// ---- two-level scan ----
__global__ __launch_bounds__(1024) void scan_part(const int* __restrict__ hist,
                                                  int* __restrict__ rowptr,
                                                  int* __restrict__ blocksum) {
    int t = threadIdx.x;
    int i = blockIdx.x * 1024 + t;
    int orig = (i < N_NODES) ? hist[i] : 0;
    int v = orig;
#pragma unroll
    for (int off = 1; off < 64; off <<= 1) {
        int u = __shfl_up(v, off);
        if ((t & 63) >= off) v += u;
    }
    __shared__ int wsum[16];
    int wid = t >> 6;
    if ((t & 63) == 63) wsum[wid] = v;
    __syncthreads();
    int woff = 0;
#pragma unroll
    for (int w = 0; w < 16; w++)
        if (w < wid) woff += wsum[w];
    int incl = v + woff;
    if (i < N_NODES) rowptr[i] = incl - orig;
    if (t == 1023) blocksum[blockIdx.x] = incl;
}

__global__ __launch_bounds__(128) void scan_block(const int* __restrict__ blocksum,
                                                  int* __restrict__ blockoff,
                                                  int* __restrict__ rowptr) {
    int t = threadIdx.x;
    int orig = (t < SCAN_BLOCKS) ? blocksum[t] : 0;
    int v = orig;
#pragma unroll
    for (int off = 1; off < 64; off <<= 1) {
        int u = __shfl_up(v, off);
        if ((t & 63) >= off) v += u;
    }
    __shared__ int w0;
    if (t == 63) w0 = v;
    __syncthreads();
    if (t >= 64) v += w0;
    if (t < SCAN_BLOCKS) blockoff[t] = v - orig;
    if (t == 0) rowptr[N_NODES] = N_EDGES;
}

__global__ __launch_bounds__(1024) void scan_add(int* __restrict__ rowptr,
                                                 const int* __restrict__ blockoff,
                                                 int* __restrict__ cursor) {
    int i = blockIdx.x * 1024 + threadIdx.x;
    if (i < N_NODES) {
        int v = rowptr[i] + blockoff[blockIdx.x];
        rowptr[i] = v;
        cursor[i] = v;
    }
}

// permute edge payloads into col-sorted order
__global__ void scatter_kernel(const int* __restrict__ erow, const int* __restrict__ ecol,
                               const float* __restrict__ ea, const float* __restrict__ dis,
                               int* __restrict__ cursor,
                               float* __restrict__ ea8, int* __restrict__ rows) {
    int e = blockIdx.x * 256 + threadIdx.x;
    int c = ecol[e];
    int r = erow[e];
    float nrm = dis[r] * dis[c];
    int pos = atomicAdd(&cursor[c], 1);
    const float* p = ea + (size_t)e * 7;
    float a0 = p[0], a1 = p[1], a2 = p[2], a3 = p[3], a4 = p[4], a5 = p[5], a6 = p[6];
    float* dst = ea8 + (size_t)pos * 8;
    *(float4*)dst = make_float4(a0, a1, a2, a3);
    *(float4*)(dst + 4) = make_float4(a4, a5, a6, nrm);
    rows[pos] = r;
}

// ================= xl = act(h) @ W + b  via MFMA f16 =================
__global__ __launch_bounds__(256) void gemm_xl(const __half* __restrict__ hsrc,
                                               const int* __restrict__ xidx,
                                               const float* __restrict__ nemb,
                                               const float* __restrict__ colsum_p,
                                               const float* __restrict__ colsumsq_p,
                                               const float* __restrict__ gamma_p,
                                               const float* __restrict__ beta_p,
                                               const float* __restrict__ Wl,
                                               const float* __restrict__ bl,
                                               __half* __restrict__ xlo, int mode) {
    __shared__ half8_t sB[2048];          // [ct][ks][lane] fragments, 32 KB
    __shared__ float sScale[H], sShift[H];
    int t = threadIdx.x;
    if (mode == 1 && t < H) {
        float mean = colsum_p[t] * (1.0f / N_NODES);
        float var = colsumsq_p[t] * (1.0f / N_NODES) - mean * mean;
        float s = gamma_p[t] * rsqrtf(var + BN_EPS);
        sScale[t] = s;
        sShift[t] = beta_p[t] - mean * s;
    }
    // stage W as B-fragments
    for (int idx = t; idx < 2048; idx += 256) {
        int ct = idx >> 8;
        int ks = (idx >> 6) & 3;
        int ln = idx & 63;
        int kbase = ks * 32 + (ln >> 4) * 8;
        int c = ct * 16 + (ln & 15);
        half8_t v;
#pragma unroll
        for (int i = 0; i < 8; i++)
            v[i] = (_Float16)Wl[(size_t)(kbase + i) * H + c];
        sB[idx] = v;
    }
    __syncthreads();

    int w = t >> 6, lane = t & 63;
    int lq = lane >> 4, lr = lane & 15;
    int rbase = blockIdx.x * 128 + w * 32;

    floatx4 acc[2][8];
#pragma unroll
    for (int rt = 0; rt < 2; rt++)
#pragma unroll
        for (int ct = 0; ct < 8; ct++) acc[rt][ct] = (floatx4)0.0f;

    float bias[8];
#pragma unroll
    for (int ct = 0; ct < 8; ct++) bias[ct] = bl[ct * 16 + lr];

    int arow[2], xv[2];
#pragma unroll
    for (int rt = 0; rt < 2; rt++) {
        int row = rbase + rt * 16 + lr;
        if (row > N_NODES - 1) row = N_NODES - 1;
        arow[rt] = row;
        if (mode == 0) xv[rt] = xidx[row];
    }

    for (int ks = 0; ks < 4; ks++) {
        int k0 = ks * 32 + lq * 8;
        half8_t a[2];
#pragma unroll
        for (int rt = 0; rt < 2; rt++) {
            float f[8];
            if (mode == 0) {
                const float* p = nemb + (size_t)xv[rt] * H + k0;
                float4 u0 = *(const float4*)p;
                float4 u1 = *(const float4*)(p + 4);
                f[0] = u0.x; f[1] = u0.y; f[2] = u0.z; f[3] = u0.w;
                f[4] = u1.x; f[5] = u1.y; f[6] = u1.z; f[7] = u1.w;
            } else {
                union { float4 f4; __half2 h2[4]; } u;
                u.f4 = *(const float4*)(hsrc + (size_t)arow[rt] * H + k0);
#pragma unroll
                for (int i = 0; i < 4; i++) {
                    float2 d = __half22float2(u.h2[i]);
                    f[2 * i] = d.x; f[2 * i + 1] = d.y;
                }
#pragma unroll
                for (int i = 0; i < 8; i++)
                    f[i] = frelu(f[i] * sScale[k0 + i] + sShift[k0 + i]);
            }
            half8_t av;
#pragma unroll
            for (int i = 0; i < 8; i++) av[i] = (_Float16)f[i];
            a[rt] = av;
        }
#pragma unroll
        for (int ct = 0; ct < 8; ct++) {
            half8_t bf = sB[(ct * 4 + ks) * 64 + lane];
            acc[0][ct] = __builtin_amdgcn_mfma_f32_16x16x32_f16(a[0], bf, acc[0][ct], 0, 0, 0);
            acc[1][ct] = __builtin_amdgcn_mfma_f32_16x16x32_f16(a[1], bf, acc[1][ct], 0, 0, 0);
        }
    }

#pragma unroll
    for (int rt = 0; rt < 2; rt++)
#pragma unroll
        for (int ct = 0; ct < 8; ct++)
#pragma unroll
            for (int r = 0; r < 4; r++) {
                int row = rbase + rt * 16 + lq * 4 + r;
                if (row < N_NODES)
                    xlo[(size_t)row * H + ct * 16 + lr] =
                        __float2half(acc[rt][ct][r] + bias[ct]);
            }
}

// ================= gather aggregation + BN stats =================
// wave per node; lane owns cols {2*lane, 2*lane+1}; xl gathered as half2;
// hpre written as half2. n/jb/je scalarized via readfirstlane; rows/payload
// loads are wave-uniform -> scalar pipe. 8-wide edge batches: 8 gathers
// in flight per wave before any consumption (MLP of batch overlaps).
__global__ __launch_bounds__(256) void agg_kernel(
    const int* __restrict__ rowptr, const float* __restrict__ ea8,
    const int* __restrict__ rows, const __half2* __restrict__ xh2,
    const float* __restrict__ invdeg, const float* __restrict__ rootl,
    const float* __restrict__ Wel, const float* __restrict__ bel,
    __half2* __restrict__ hpreh, float* __restrict__ colsum,
    float* __restrict__ colsumsq) {
    int t = threadIdx.x;
    int lane = t & 63, wv = t >> 6;
    int c0 = lane * 2;
    float w00 = Wel[0 * H + c0], w01 = Wel[0 * H + c0 + 1];
    float w10 = Wel[1 * H + c0], w11 = Wel[1 * H + c0 + 1];
    float w20 = Wel[2 * H + c0], w21 = Wel[2 * H + c0 + 1];
    float w30 = Wel[3 * H + c0], w31 = Wel[3 * H + c0 + 1];
    float w40 = Wel[4 * H + c0], w41 = Wel[4 * H + c0 + 1];
    float w50 = Wel[5 * H + c0], w51 = Wel[5 * H + c0 + 1];
    float w60 = Wel[6 * H + c0], w61 = Wel[6 * H + c0 + 1];
    float be0 = bel[c0], be1 = bel[c0 + 1];
    float rt0 = rootl[c0], rt1 = rootl[c0 + 1];
    float s0 = 0, s1 = 0, q0 = 0, q1 = 0;

#define MLP_BODY(V0, V1, XG)                                                 \
    {                                                                        \
        float2 xg_ = __half22float2(XG);                                     \
        float m0_ = be0, m1_ = be1;                                          \
        m0_ = fmaf((V0).x, w00, m0_); m1_ = fmaf((V0).x, w01, m1_);          \
        m0_ = fmaf((V0).y, w10, m0_); m1_ = fmaf((V0).y, w11, m1_);          \
        m0_ = fmaf((V0).z, w20, m0_); m1_ = fmaf((V0).z, w21, m1_);          \
        m0_ = fmaf((V0).w, w30, m0_); m1_ = fmaf((V0).w, w31, m1_);          \
        m0_ = fmaf((V1).x, w40, m0_); m1_ = fmaf((V1).x, w41, m1_);          \
        m0_ = fmaf((V1).y, w50, m0_); m1_ = fmaf((V1).y, w51, m1_);          \
        m0_ = fmaf((V1).z, w60, m0_); m1_ = fmaf((V1).z, w61, m1_);          \
        a0 = fmaf(frelu(xg_.x + m0_), (V1).w, a0);                           \
        a1 = fmaf(frelu(xg_.y + m1_), (V1).w, a1);                           \
    }

    for (int n_ = blockIdx.x * 4 + wv; n_ < N_NODES; n_ += gridDim.x * 4) {
        int n = __builtin_amdgcn_readfirstlane(n_);
        int jb = __builtin_amdgcn_readfirstlane(rowptr[n]);
        int je = __builtin_amdgcn_readfirstlane(rowptr[n + 1]);
        float a0 = 0, a1 = 0;
        int j = jb;
        for (; j + 8 <= je; j += 8) {
            int rr[8];
#pragma unroll
            for (int i = 0; i < 8; i++) rr[i] = rows[j + i];
            __half2 g[8];
#pragma unroll
            for (int i = 0; i < 8; i++) g[i] = xh2[(size_t)rr[i] * 64 + lane];
#pragma unroll
            for (int i = 0; i < 8; i++) {
                const float* ep_ = ea8 + (size_t)(j + i) * 8;
                float4 va = *(const float4*)ep_, vb = *(const float4*)(ep_ + 4);
                MLP_BODY(va, vb, g[i]);
            }
        }
        if (j + 4 <= je) {
            int rr[4];
#pragma unroll
            for (int i = 0; i < 4; i++) rr[i] = rows[j + i];
            __half2 g[4];
#pragma unroll
            for (int i = 0; i < 4; i++) g[i] = xh2[(size_t)rr[i] * 64 + lane];
#pragma unroll
            for (int i = 0; i < 4; i++) {
                const float* ep_ = ea8 + (size_t)(j + i) * 8;
                float4 va = *(const float4*)ep_, vb = *(const float4*)(ep_ + 4);
                MLP_BODY(va, vb, g[i]);
            }
            j += 4;
        }
        for (; j < je; j++) {
            int r_ = rows[j];
            const float* ep_ = ea8 + (size_t)j * 8;
            float4 va = *(const float4*)ep_, vb = *(const float4*)(ep_ + 4);
            __half2 g_ = xh2[(size_t)r_ * 64 + lane];
            MLP_BODY(va, vb, g_);
        }
        float2 xn = __half22float2(xh2[(size_t)n * 64 + lane]);
        float id = invdeg[n];
        float p0 = a0 + frelu(xn.x + rt0) * id;
        float p1 = a1 + frelu(xn.y + rt1) * id;
        hpreh[(size_t)n * 64 + lane] = __float22half2_rn(make_float2(p0, p1));
        s0 += p0; s1 += p1;
        q0 = fmaf(p0, p0, q0); q1 = fmaf(p1, p1, q1);
    }
#undef MLP_BODY

    __shared__ float red[4][H];
    red[wv][c0] = s0; red[wv][c0 + 1] = s1;
    __syncthreads();
    if (wv == 0) {
        float t0 = red[0][c0] + red[1][c0] + red[2][c0] + red[3][c0];
        float t1 = red[0][c0 + 1] + red[1][c0 + 1] + red[2][c0 + 1] + red[3][c0 + 1];
        unsafeAtomicAdd(&colsum[c0], t0);
        unsafeAtomicAdd(&colsum[c0 + 1], t1);
    }
    __syncthreads();
    red[wv][c0] = q0; red[wv][c0 + 1] = q1;
    __syncthreads();
    if (wv == 0) {
        float t0 = red[0][c0] + red[1][c0] + red[2][c0] + red[3][c0];
        float t1 = red[0][c0 + 1] + red[1][c0 + 1] + red[2][c0 + 1] + red[3][c0 + 1];
        unsafeAtomicAdd(&colsumsq[c0], t0);
        unsafeAtomicAdd(&colsumsq[c0 + 1], t1);
    }
}

// ================= pool (applies final BN in-kernel, fp16 input) =================
__global__ __launch_bounds__(256) void pool_kernel(const __half2* __restrict__ hh,
                                                   const int* __restrict__ batch,
                                                   const float* __restrict__ colsum_p,
                                                   const float* __restrict__ colsumsq_p,
                                                   const float* __restrict__ gamma_p,
                                                   const float* __restrict__ beta_p,
                                                   float* __restrict__ pooled,
                                                   float* __restrict__ cnt) {
    __shared__ float sScale[H], sShift[H];
    int t = threadIdx.x;
    if (t < H) {
        float mean = colsum_p[t] * (1.0f / N_NODES);
        float var = colsumsq_p[t] * (1.0f / N_NODES) - mean * mean;
        float s = gamma_p[t] * rsqrtf(var + BN_EPS);
        sScale[t] = s;
        sShift[t] = beta_p[t] - mean * s;
    }
    __syncthreads();
    int cg = t & 63, rg = t >> 6;
    int c0 = cg * 2;
    float sc0 = sScale[c0], sc1 = sScale[c0 + 1];
    float sh0 = sShift[c0], sh1 = sShift[c0 + 1];
    int per = (N_NODES + gridDim.x - 1) / gridDim.x;
    int rstart = blockIdx.x * per;
    int rend = min(rstart + per, N_NODES);
    float a0 = 0, a1 = 0, runc = 0.0f;
    int cur = -1;
    for (int rowi = rstart + rg; rowi < rend; rowi += 4) {
        int g = batch[rowi];
        if (g != cur) {
            if (cur >= 0) {
                unsafeAtomicAdd(&pooled[(size_t)cur * H + c0 + 0], a0);
                unsafeAtomicAdd(&pooled[(size_t)cur * H + c0 + 1], a1);
                if (cg == 0) unsafeAtomicAdd(&cnt[cur], runc);
            }
            cur = g; a0 = 0; a1 = 0; runc = 0.0f;
        }
        float2 v = __half22float2(hh[(size_t)rowi * 64 + cg]);
        a0 += v.x * sc0 + sh0;
        a1 += v.y * sc1 + sh1;
        runc += 1.0f;
    }
    if (cur >= 0) {
        unsafeAtomicAdd(&pooled[(size_t)cur * H + c0 + 0], a0);
        unsafeAtomicAdd(&pooled[(size_t)cur * H + c0 + 1], a1);
        if (cg == 0) unsafeAtomicAdd(&cnt[cur], runc);
    }
}

__global__ __launch_bounds__(128) void final_gemm(const float* __restrict__ pooled,
                                                  const float* __restrict__ cnt,
                                                  const float* __restrict__ Wout,
                                                  const float* __restrict__ bout,
                                                  float* __restrict__ out) {
    __shared__ float sh[H];
    int g = blockIdx.x;
    int o = threadIdx.x;
    float c = fmaxf(cnt[g], 1.0f);
    sh[o] = pooled[(size_t)g * H + o] / c;
    __syncthreads();
    float acc = bout[o];
#pragma unroll 8
    for (int k = 0; k < H; k++) acc += sh[k] * Wout[(size_t)k * OUT_F + o];
    out[(size_t)g * OUT_F + o] = acc;
}

extern "C" void kernel_launch(void* const* d_in, const int* in_sizes, int n_in,
                              void* d_out, int out_size, void* d_ws, size_t ws_size,
                              hipStream_t stream) {
    const int*   x     = (const int*)d_in[0];
    const int*   ei    = (const int*)d_in[1];
    const float* ea    = (const float*)d_in[2];
    const int*   batch = (const int*)d_in[3];
    const float* nemb  = (const float*)d_in[4];
    const float* W     = (const float*)d_in[5];
    const float* b     = (const float*)d_in[6];
    const float* We    = (const float*)d_in[7];
    const float* be    = (const float*)d_in[8];
    const float* root  = (const float*)d_in[9];
    const float* gamma = (const float*)d_in[10];
    const float* beta  = (const float*)d_in[11];
    const float* Wout  = (const float*)d_in[12];
    const float* bout  = (const float*)d_in[13];
    float* out = (float*)d_out;

    const int* erow = ei;
    const int* ecol = ei + N_EDGES;

    float* ws = (float*)d_ws;
    size_t NH = (size_t)N_NODES * H;
    float* ea8    = ws;                                  // E*8 floats
    int*   rows   = (int*)(ea8 + (size_t)N_EDGES * 8);   // E ints
    float* hslot  = (float*)(rows + N_EDGES);            // NH/2 floats (fp16 hpre)
    __half* hpreh = (__half*)hslot;
    float* xslot  = hslot + NH / 2;                      // NH/2 floats (fp16 xl)
    __half* xlh   = (__half*)xslot;
    int*   rowptr = (int*)(xslot + NH / 2);              // N+1 (+pad)
    float* dis    = (float*)(rowptr + N_NODES + 4);
    float* invdeg = dis + N_NODES;
    float* colsumAll = invdeg + N_NODES;                 // L*2*H floats
    float* pooled   = colsumAll + (size_t)L_LAYERS * 2 * H;
    float* cnt      = pooled + (size_t)G_GRAPHS * H;
    int*   blocksum = (int*)(cnt + G_GRAPHS);            // 128
    int*   blockoff = blocksum + 128;                    // 128

    // preprocessing temps alias into hpre region (hpre first written in layer 0 agg)
    int* degcnt = (int*)hslot;
    int* hist   = degcnt + N_NODES;
    int* cursor = hist + N_NODES;

    hipMemsetAsync(degcnt, 0, 2 * N_NODES * sizeof(int), stream);
    hipMemsetAsync(colsumAll, 0, (size_t)L_LAYERS * 2 * H * sizeof(float), stream);
    hipLaunchKernelGGL(count_kernel, dim3(N_EDGES / 256), dim3(256), 0, stream,
                       erow, ecol, degcnt, hist);
    hipLaunchKernelGGL(finish_deg, dim3((N_NODES + 255) / 256), dim3(256), 0, stream,
                       degcnt, dis, invdeg);
    hipLaunchKernelGGL(scan_part, dim3(SCAN_BLOCKS), dim3(1024), 0, stream,
                       hist, rowptr, blocksum);
    hipLaunchKernelGGL(scan_block, dim3(1), dim3(128), 0, stream,
                       blocksum, blockoff, rowptr);
    hipLaunchKernelGGL(scan_add, dim3(SCAN_BLOCKS), dim3(1024), 0, stream,
                       rowptr, blockoff, cursor);
    hipLaunchKernelGGL(scatter_kernel, dim3(N_EDGES / 256), dim3(256), 0, stream,
                       erow, ecol, ea, dis, cursor, ea8, rows);

    for (int l = 0; l < L_LAYERS; l++) {
        const float* cs_prev = colsumAll + (size_t)(l - 1) * 2 * H;  // unused when l==0
        hipLaunchKernelGGL(gemm_xl, dim3((N_NODES + 127) / 128), dim3(256), 0, stream,
                           hpreh, x, nemb,
                           (l == 0) ? colsumAll : cs_prev,
                           (l == 0) ? colsumAll : cs_prev + H,
                           gamma + (size_t)(l ? l - 1 : 0) * H,
                           beta + (size_t)(l ? l - 1 : 0) * H,
                           W + (size_t)l * H * H, b + (size_t)l * H, xlh,
                           (l == 0) ? 0 : 1);
        float* cs = colsumAll + (size_t)l * 2 * H;
        hipLaunchKernelGGL(agg_kernel, dim3(2048), dim3(256), 0, stream,
                           rowptr, ea8, rows, (const __half2*)xlh, invdeg,
                           root + (size_t)l * H, We + (size_t)l * 7 * H, be + (size_t)l * H,
                           (__half2*)hpreh, cs, cs + H);
    }

    hipMemsetAsync(pooled, 0, ((size_t)G_GRAPHS * H + G_GRAPHS) * sizeof(float), stream);
    {
        const float* cs4 = colsumAll + (size_t)(L_LAYERS - 1) * 2 * H;
        hipLaunchKernelGGL(pool_kernel, dim3(256), dim3(256), 0, stream,
                           (const __half2*)hpreh, batch, cs4, cs4 + H,
                           gamma + (size_t)(L_LAYERS - 1) * H,
                           beta + (size_t)(L_LAYERS - 1) * H, pooled, cnt);
    }
    hipLaunchKernelGGL(final_gemm, dim3(G_GRAPHS), dim3(OUT_F), 0, stream,
                       pooled, cnt, Wout, bout, out);
}